// Round 3
// baseline (298.809 us; speedup 1.0000x reference)
//
#include <hip/hip_runtime.h>
#include <math.h>

// Problem constants
constexpr int D     = 1024;
constexpr int NH    = 16;
constexpr int HD    = 64;
constexpr int SEQ   = 2048;
constexpr int BATCH = 4;
constexpr int NTOK  = BATCH * SEQ;   // 8192 rows

typedef short s16x8 __attribute__((ext_vector_type(8)));
typedef short s16x4 __attribute__((ext_vector_type(4)));
typedef float f32x4 __attribute__((ext_vector_type(4)));
typedef unsigned short u16;
typedef unsigned int   u32;

#if __has_builtin(__builtin_amdgcn_exp2f)
#define EXP2(x) __builtin_amdgcn_exp2f(x)
#else
#define EXP2(x) exp2f(x)
#endif

__device__ __forceinline__ short f2bf(float f) {
    unsigned u = __float_as_uint(f);
    unsigned r = (u + 0x7FFFu + ((u >> 16) & 1u)) >> 16;   // RNE
    return (short)r;
}
__device__ __forceinline__ float bf2f(u16 s) {
    return __uint_as_float(((unsigned)s) << 16);
}

// pack hi16(f1)|hi16(f0) -> one u32 (lo = f0) via v_perm_b32
__device__ __forceinline__ u32 pack_bf16_pair(float f0, float f1) {
    u32 a = __float_as_uint(f1) + 0x8000u;   // round half up
    u32 b = __float_as_uint(f0) + 0x8000u;
    return __builtin_amdgcn_perm(a, b, 0x07060302u);
}

__device__ __forceinline__ void async_lds16(const void* g, void* l) {
    __builtin_amdgcn_global_load_lds(
        (const __attribute__((address_space(1))) unsigned int*)g,
        (__attribute__((address_space(3))) unsigned int*)l, 16, 0, 0);
}

// ---------------------------------------------------------------------------
// Reductions (wave = 64)
// ---------------------------------------------------------------------------
__device__ __forceinline__ float block_reduce_sum(float v, float* red) {
    int lane = threadIdx.x & 63, wid = threadIdx.x >> 6;
    #pragma unroll
    for (int off = 32; off > 0; off >>= 1) v += __shfl_down(v, off, 64);
    if (lane == 0) red[wid] = v;
    __syncthreads();
    float r = red[0] + red[1] + red[2] + red[3];
    __syncthreads();
    return r;
}

// ---------------------------------------------------------------------------
// 1) LayerNorm (fp32 math) -> bf16 h
// ---------------------------------------------------------------------------
__global__ __launch_bounds__(256) void ln_kernel(const float* __restrict__ x,
                                                 const float* __restrict__ w,
                                                 const float* __restrict__ b,
                                                 u16* __restrict__ h) {
    __shared__ float red[4];
    int row = blockIdx.x;
    const float* xr = x + (size_t)row * D;
    int t = threadIdx.x;
    float v[4];
    float s = 0.f;
    #pragma unroll
    for (int i = 0; i < 4; i++) { v[i] = xr[t + 256 * i]; s += v[i]; }
    float mean = block_reduce_sum(s, red) * (1.0f / 1024.0f);
    float ss = 0.f;
    #pragma unroll
    for (int i = 0; i < 4; i++) { float d = v[i] - mean; ss += d * d; }
    float var = block_reduce_sum(ss, red) * (1.0f / 1024.0f);
    float rstd = rsqrtf(var + 1e-5f);
    u16* hr = h + (size_t)row * D;
    #pragma unroll
    for (int i = 0; i < 4; i++) {
        int c = t + 256 * i;
        hr[c] = (u16)f2bf((v[i] - mean) * rstd * w[c] + b[c]);
    }
}

// ---------------------------------------------------------------------------
// 1b) fp32 -> bf16 cast (weights); n divisible by 1024
// ---------------------------------------------------------------------------
__global__ __launch_bounds__(256) void cast_kernel(const float* __restrict__ in,
                                                   u16* __restrict__ out, int n) {
    int i = (blockIdx.x * 256 + threadIdx.x) * 4;
    if (i >= n) return;
    float4 f = *(const float4*)(in + i);
    s16x4 o4;
    o4[0] = f2bf(f.x); o4[1] = f2bf(f.y); o4[2] = f2bf(f.z); o4[3] = f2bf(f.w);
    *(s16x4*)(out + i) = o4;
}

// ---------------------------------------------------------------------------
// 2) bf16 MFMA GEMM (m97 structure, 128x128): C = A @ B^T + bias (+R).
//    Reinstated for QKV: at K=1024 / grid 1536 (6 blocks/CU sequential,
//    3 co-resident) the implicit inter-block overlap beats the 256^2
//    8-phase template (which measured 103.6 us: 1 block/CU, 1.5-round
//    tail, A-panel L2 reuse lost -> latency-bound at MfmaUtil 19%).
//    NORMK: fused k L2-normalization (wave's 64-col span == one head).
// ---------------------------------------------------------------------------
template <typename OutT, bool RES, bool NORMK>
__global__ __launch_bounds__(256) void gemm_bf16(const u16* __restrict__ A,
                                                 const u16* __restrict__ B,
                                                 const float* __restrict__ bias,
                                                 const float* __restrict__ R,
                                                 OutT* __restrict__ C,
                                                 int M, int N, int K) {
    __shared__ u16 As[128 * 32];
    __shared__ u16 Bs[128 * 32];
    int tid = threadIdx.x, wave = tid >> 6, lane = tid & 63;
    int quad = lane >> 4, l16 = lane & 15;
    int wm = (wave & 1) * 64, wn = (wave >> 1) * 64;
    int rowBase = blockIdx.y * 128, colBase = blockIdx.x * 128;

    int srow = lane >> 2;
    int sk8  = (lane & 3) * 8;

    f32x4 acc[4][4];
    #pragma unroll
    for (int i = 0; i < 4; i++)
        #pragma unroll
        for (int j = 0; j < 4; j++)
            acc[i][j] = (f32x4){0.f, 0.f, 0.f, 0.f};

    for (int k0 = 0; k0 < K; k0 += 32) {
        __syncthreads();
        #pragma unroll
        for (int i = 0; i < 2; i++) {
            int r = wave * 32 + i * 16;
            const u16* ga = A + (size_t)(rowBase + r + srow) * K + k0 + sk8;
            async_lds16(ga, &As[r * 32]);
            const u16* gb = B + (size_t)(colBase + r + srow) * K + k0 + sk8;
            async_lds16(gb, &Bs[r * 32]);
        }
        __syncthreads();

        s16x8 af[4], bfr[4];
        #pragma unroll
        for (int t = 0; t < 4; t++) {
            af[t]  = *(const s16x8*)&As[(wm + t * 16 + l16) * 32 + quad * 8];
            bfr[t] = *(const s16x8*)&Bs[(wn + t * 16 + l16) * 32 + quad * 8];
        }
        #pragma unroll
        for (int mt = 0; mt < 4; mt++)
            #pragma unroll
            for (int nt = 0; nt < 4; nt++)
                acc[mt][nt] = __builtin_amdgcn_mfma_f32_16x16x32_bf16(
                    af[mt], bfr[nt], acc[mt][nt], 0, 0, 0);
    }

    // wave-uniform: does this wave's 64-col span hold k values?
    bool normk = NORMK && (colBase + wn) >= 1024 && (colBase + wn) < 2048;

    #pragma unroll
    for (int mt = 0; mt < 4; mt++) {
        float vals[4][4];   // [nt][r]
        #pragma unroll
        for (int nt = 0; nt < 4; nt++) {
            int gn = colBase + wn + nt * 16 + l16;
            float bv = bias[gn];
            #pragma unroll
            for (int r = 0; r < 4; r++) {
                float val = acc[mt][nt][r] + bv;
                if (RES) {
                    int gm = rowBase + wm + mt * 16 + quad * 4 + r;
                    val += R[(size_t)gm * N + gn];
                }
                vals[nt][r] = val;
            }
        }
        if (normk) {
            #pragma unroll
            for (int r = 0; r < 4; r++) {
                float ssq = 0.f;
                #pragma unroll
                for (int nt = 0; nt < 4; nt++) ssq = fmaf(vals[nt][r], vals[nt][r], ssq);
                ssq += __shfl_xor(ssq, 1, 64);
                ssq += __shfl_xor(ssq, 2, 64);
                ssq += __shfl_xor(ssq, 4, 64);
                ssq += __shfl_xor(ssq, 8, 64);
                float inv = 1.0f / fmaxf(sqrtf(ssq), 1e-12f);
                #pragma unroll
                for (int nt = 0; nt < 4; nt++) vals[nt][r] *= inv;
            }
        }
        #pragma unroll
        for (int nt = 0; nt < 4; nt++) {
            int gn = colBase + wn + nt * 16 + l16;
            int gm0 = rowBase + wm + mt * 16 + quad * 4;
            #pragma unroll
            for (int r = 0; r < 4; r++) {
                if constexpr (sizeof(OutT) == 2)
                    C[(size_t)(gm0 + r) * N + gn] = (OutT)f2bf(vals[nt][r]);
                else
                    C[(size_t)(gm0 + r) * N + gn] = vals[nt][r];
            }
        }
    }
}

// ---------------------------------------------------------------------------
// 3) 256x256 8-phase bf16 MFMA GEMM (m201 template) -- kept for OUT-PROJ
//    only (N=1024: whole B panel L2-resident, single 128-block launch
//    measured ~8 us better than m97 here). See round-2 notes: not used for
//    QKV (1.5-round tail + A-panel L2 thrash made it latency-bound).
// ---------------------------------------------------------------------------
__device__ __forceinline__ s16x8 rdfrag(const u16* lds, int row, int kk, int quad) {
    int byte = row * 128 + ((kk * 64 + quad * 16) ^ ((row & 7) << 4));
    return *(const s16x8*)((const char*)lds + byte);
}

__device__ __forceinline__ void stage_half_A(const u16* __restrict__ A, u16* ldsA,
                                             int rowBase, int K, int kt, int hs,
                                             int wave, int lane) {
    #pragma unroll
    for (int i = 0; i < 2; i++) {
        int c = wave * 2 + i;
        int baserow = ((c & 7) * 8) + ((c >> 3) << 7) + (hs << 6);
        int row = baserow + (lane >> 3);
        int colb = ((lane & 7) * 16) ^ ((row & 7) << 4);
        const u16* src = A + (size_t)(rowBase + row) * K + kt * 64 + (colb >> 1);
        async_lds16(src, ldsA + baserow * 64);
    }
}
__device__ __forceinline__ void stage_half_B(const u16* __restrict__ B, u16* ldsB,
                                             int colBase, int K, int kt, int hs,
                                             int wave, int lane) {
    #pragma unroll
    for (int i = 0; i < 2; i++) {
        int c = wave * 2 + i;
        int baserow = ((c & 3) * 8) + ((c >> 2) << 6) + (hs << 5);
        int row = baserow + (lane >> 3);
        int colb = ((lane & 7) * 16) ^ ((row & 7) << 4);
        const u16* src = B + (size_t)(colBase + row) * K + kt * 64 + (colb >> 1);
        async_lds16(src, ldsB + baserow * 64);
    }
}

template <typename OutT, bool RES, bool NORMK>
__global__ __launch_bounds__(512, 2) void gemm256(const u16* __restrict__ A,
                                                  const u16* __restrict__ B,
                                                  const float* __restrict__ bias,
                                                  const float* __restrict__ R,
                                                  OutT* __restrict__ C,
                                                  int M, int N, int K) {
    __shared__ u16 lds[2][2][256 * 64];   // [buf][A,B][row*64+col], 128 KiB

    int nby = M >> 8;
    int cpx = gridDim.x >> 3;
    int bid = blockIdx.x;
    int swz = (bid & 7) * cpx + (bid >> 3);
    int bx = swz / nby, by = swz % nby;   // M-fast walk: XCD reuses B panel
    int rowBase = by << 8, colBase = bx << 8;

    int tid = threadIdx.x, wave = tid >> 6, lane = tid & 63;
    int quad = lane >> 4, l16 = lane & 15;
    int wr = wave >> 2, wc = wave & 3;    // 2M x 4N wave grid
    int KT = K >> 6;                      // 64-wide K tiles

    f32x4 acc[8][4];
    #pragma unroll
    for (int m = 0; m < 8; m++)
        #pragma unroll
        for (int n = 0; n < 4; n++)
            acc[m][n] = (f32x4){0.f, 0.f, 0.f, 0.f};

    // ---- prologue: tile0 full + tile1 {A-mlo,B-nlo,A-mhi}; drain tile0 ----
    stage_half_A(A, &lds[0][0][0], rowBase, K, 0, 0, wave, lane);
    stage_half_B(B, &lds[0][1][0], colBase, K, 0, 0, wave, lane);
    stage_half_A(A, &lds[0][0][0], rowBase, K, 0, 1, wave, lane);
    stage_half_B(B, &lds[0][1][0], colBase, K, 0, 1, wave, lane);
    stage_half_A(A, &lds[1][0][0], rowBase, K, 1, 0, wave, lane);
    stage_half_B(B, &lds[1][1][0], colBase, K, 1, 0, wave, lane);
    stage_half_A(A, &lds[1][0][0], rowBase, K, 1, 1, wave, lane);
    asm volatile("s_waitcnt vmcnt(6)" ::: "memory");
    __builtin_amdgcn_s_barrier();

    for (int t = 0; t < KT; ++t) {
        int bsel = t & 1;
        u16* cA = &lds[bsel][0][0];
        u16* cB = &lds[bsel][1][0];
        u16* oB = &lds[bsel ^ 1][1][0];
        int t1 = t + 1; if (t1 >= KT) t1 -= KT;   // wrap: tail prefetch harmless
        int t2 = t + 2; if (t2 >= KT) t2 -= KT;

        s16x8 af[4][2], bf0[2][2], bf1[2][2];

        // ---- phase 1: read A m0-3 + B n0-1 (12 rd); stage B-nhi(t+1) ----
        #pragma unroll
        for (int m = 0; m < 4; m++)
            #pragma unroll
            for (int kk = 0; kk < 2; kk++)
                af[m][kk] = rdfrag(cA, wr * 128 + m * 16 + l16, kk, quad);
        #pragma unroll
        for (int n = 0; n < 2; n++)
            #pragma unroll
            for (int kk = 0; kk < 2; kk++)
                bf0[n][kk] = rdfrag(cB, wc * 64 + n * 16 + l16, kk, quad);
        stage_half_B(B, oB, colBase, K, t1, 1, wave, lane);
        __builtin_amdgcn_s_barrier();
        __builtin_amdgcn_s_setprio(1);
        #pragma unroll
        for (int kk = 0; kk < 2; kk++)
            #pragma unroll
            for (int m = 0; m < 4; m++)
                #pragma unroll
                for (int n = 0; n < 2; n++)
                    acc[m][n] = __builtin_amdgcn_mfma_f32_16x16x32_bf16(
                        af[m][kk], bf0[n][kk], acc[m][n], 0, 0, 0);
        __builtin_amdgcn_s_setprio(0);
        __builtin_amdgcn_s_barrier();

        // ---- phase 2: read B n2-3 (4 rd); stage A-mlo(t+2) ----
        #pragma unroll
        for (int n = 0; n < 2; n++)
            #pragma unroll
            for (int kk = 0; kk < 2; kk++)
                bf1[n][kk] = rdfrag(cB, wc * 64 + (n + 2) * 16 + l16, kk, quad);
        stage_half_A(A, cA, rowBase, K, t2, 0, wave, lane);
        __builtin_amdgcn_s_barrier();
        __builtin_amdgcn_s_setprio(1);
        #pragma unroll
        for (int kk = 0; kk < 2; kk++)
            #pragma unroll
            for (int m = 0; m < 4; m++)
                #pragma unroll
                for (int n = 0; n < 2; n++)
                    acc[m][n + 2] = __builtin_amdgcn_mfma_f32_16x16x32_bf16(
                        af[m][kk], bf1[n][kk], acc[m][n + 2], 0, 0, 0);
        __builtin_amdgcn_s_setprio(0);
        __builtin_amdgcn_s_barrier();

        // ---- phase 3: read A m4-7 (8 rd); stage B-nlo(t+2) ----
        #pragma unroll
        for (int m = 0; m < 4; m++)
            #pragma unroll
            for (int kk = 0; kk < 2; kk++)
                af[m][kk] = rdfrag(cA, wr * 128 + (m + 4) * 16 + l16, kk, quad);
        stage_half_B(B, cB, colBase, K, t2, 0, wave, lane);
        __builtin_amdgcn_s_barrier();
        __builtin_amdgcn_s_setprio(1);
        #pragma unroll
        for (int kk = 0; kk < 2; kk++)
            #pragma unroll
            for (int m = 0; m < 4; m++)
                #pragma unroll
                for (int n = 0; n < 2; n++)
                    acc[m + 4][n] = __builtin_amdgcn_mfma_f32_16x16x32_bf16(
                        af[m][kk], bf0[n][kk], acc[m + 4][n], 0, 0, 0);
        __builtin_amdgcn_s_setprio(0);
        __builtin_amdgcn_s_barrier();

        // ---- phase 4: no reads; stage A-mhi(t+2); vmcnt(6) checkpoint ----
        stage_half_A(A, cA, rowBase, K, t2, 1, wave, lane);
        __builtin_amdgcn_s_barrier();
        __builtin_amdgcn_s_setprio(1);
        #pragma unroll
        for (int kk = 0; kk < 2; kk++)
            #pragma unroll
            for (int m = 0; m < 4; m++)
                #pragma unroll
                for (int n = 0; n < 2; n++)
                    acc[m + 4][n + 2] = __builtin_amdgcn_mfma_f32_16x16x32_bf16(
                        af[m][kk], bf1[n][kk], acc[m + 4][n + 2], 0, 0, 0);
        __builtin_amdgcn_s_setprio(0);
        asm volatile("s_waitcnt vmcnt(6)" ::: "memory");
        __builtin_amdgcn_s_barrier();
    }
    asm volatile("s_waitcnt vmcnt(0)" ::: "memory");

    // ---- epilogue ----
    bool normk = NORMK && (colBase + wc * 64) >= 1024 && (colBase + wc * 64) < 2048;

    #pragma unroll
    for (int m = 0; m < 8; m++) {
        float vals[4][4];   // [n][r]
        #pragma unroll
        for (int n = 0; n < 4; n++) {
            int gn = colBase + wc * 64 + n * 16 + l16;
            float bv = bias[gn];
            #pragma unroll
            for (int r = 0; r < 4; r++) {
                float val = acc[m][n][r] + bv;
                if (RES) {
                    int gm = rowBase + wr * 128 + m * 16 + quad * 4 + r;
                    val += R[(size_t)gm * N + gn];
                }
                vals[n][r] = val;
            }
        }
        if (normk) {
            #pragma unroll
            for (int r = 0; r < 4; r++) {
                float ssq = 0.f;
                #pragma unroll
                for (int n = 0; n < 4; n++) ssq = fmaf(vals[n][r], vals[n][r], ssq);
                ssq += __shfl_xor(ssq, 1, 64);
                ssq += __shfl_xor(ssq, 2, 64);
                ssq += __shfl_xor(ssq, 4, 64);
                ssq += __shfl_xor(ssq, 8, 64);
                float inv = 1.0f / fmaxf(sqrtf(ssq), 1e-12f);
                #pragma unroll
                for (int n = 0; n < 4; n++) vals[n][r] *= inv;
            }
        }
        #pragma unroll
        for (int n = 0; n < 4; n++) {
            int gn = colBase + wc * 64 + n * 16 + l16;
            int gm0 = rowBase + wr * 128 + m * 16 + quad * 4;
            #pragma unroll
            for (int r = 0; r < 4; r++) {
                if constexpr (sizeof(OutT) == 2)
                    C[(size_t)(gm0 + r) * N + gn] = (OutT)f2bf(vals[n][r]);
                else
                    C[(size_t)(gm0 + r) * N + gn] = vals[n][r];
            }
        }
    }
}

// ---------------------------------------------------------------------------
// 4) MFMA flash attention v8 = v6 + double-buffered K/V LDS.
//    Block = one (b,h) x 256 q-rows; 4 waves x 64 q-rows.
//    v8 change: Ks/Vt are 2-deep; per kb we write buf[kb&1] then ONE
//    __syncthreads (was two). Safety: reads of buf[b] in iter kb complete
//    before barrier(kb+1); writes to buf[b] in iter kb+2 start after it.
//    Removes one full-wave barrier drain per kb (x32) from the serial
//    chain of this latency-bound kernel (round-0: MfmaUtil 38%, all
//    pipes <50%, 2 blocks/CU).
//    * Ks: [64][64] 16B-chunk XOR swizzle -> conflict-free b128 r/w.
//    * Vt: transposed, stride 68 u16.
//    * S^T = mfma(K, SCL*Q, C=-SCL); p = exp2(s); P register-resident.
//    * lsum via all-ones A-frag MFMA sum tile.
//    k pre-normalized by QKV GEMM epilogue; q normalized here.
// ---------------------------------------------------------------------------
__global__ __launch_bounds__(256, 2) void mha_kernel(const u16* __restrict__ qkv,
                                                     u16* __restrict__ out) {
    __shared__ u16 Ks[2][64 * 64];
    constexpr int VS = 68;            // Vt row stride (u16): 136 B
    __shared__ u16 Vt[2][64 * VS];

    int bh = blockIdx.x & 63;         // XCD-locality swizzle
    int qt = blockIdx.x >> 6;         // 8 q-tiles of 256 rows
    int b  = bh >> 4, h = bh & 15;
    int tid = threadIdx.x;
    int wave = tid >> 6, lane = tid & 63;
    int quad = lane >> 4, l16 = lane & 15;

    const size_t rs = 3072;
    constexpr float SCL = 11.5415605f;   // 8 * log2(e)

    // --- Q frags: load raw q, L2-normalize in-register, fold SCL ---
    s16x8 aq[4][2];
    #pragma unroll
    for (int rt = 0; rt < 4; rt++) {
        const u16* qb = qkv + ((size_t)(b * SEQ) + qt * 256 + wave * 64 + rt * 16 + l16) * rs + h * 64;
        s16x8 r0 = *(const s16x8*)(qb + quad * 8);
        s16x8 r1 = *(const s16x8*)(qb + 32 + quad * 8);
        float f0[8], f1[8], ss = 0.f;
        #pragma unroll
        for (int i = 0; i < 8; i++) { f0[i] = bf2f((u16)r0[i]); ss = fmaf(f0[i], f0[i], ss); }
        #pragma unroll
        for (int i = 0; i < 8; i++) { f1[i] = bf2f((u16)r1[i]); ss = fmaf(f1[i], f1[i], ss); }
        ss += __shfl_xor(ss, 16, 64);
        ss += __shfl_xor(ss, 32, 64);
        float inv = SCL / fmaxf(sqrtf(ss), 1e-12f);
        #pragma unroll
        for (int i = 0; i < 8; i++) {
            aq[rt][0][i] = f2bf(f0[i] * inv);
            aq[rt][1][i] = f2bf(f1[i] * inv);
        }
    }

    const f32x4 cinit = {-SCL, -SCL, -SCL, -SCL};
    f32x4 o2[4][4];    // O^T frags: lane holds d=ht*16+quad*4+r, qrow=l16
    f32x4 osum[4];     // ones-tile accumulators: lsum[rt] = osum[rt][0]
    #pragma unroll
    for (int rt = 0; rt < 4; rt++) {
        #pragma unroll
        for (int ht = 0; ht < 4; ht++) o2[rt][ht] = (f32x4){0.f, 0.f, 0.f, 0.f};
        osum[rt] = (f32x4){0.f, 0.f, 0.f, 0.f};
    }
    s16x8 ones;
    #pragma unroll
    for (int i = 0; i < 8; i++) ones[i] = (short)0x3F80;   // bf16 1.0

    // staging assignments
    int skey = tid >> 2, c4 = tid & 3;            // K: row skey, chunks 2c4,2c4+1
    int ksw  = skey & 7;                          // K swizzle key
    int vp2 = tid >> 3, dc = (tid & 7) * 8;       // V: key pair (2vp2,2vp2+1)
    const u16* kglob  = qkv + ((size_t)(b * SEQ) + skey) * rs + 1024 + h * 64 + c4 * 16;
    const u16* vglob0 = qkv + ((size_t)(b * SEQ) + 2 * vp2) * rs + 2048 + h * 64 + dc;
    int koff0 = skey * 64 + ((2 * c4)     ^ ksw) * 8;
    int koff1 = skey * 64 + ((2 * c4 + 1) ^ ksw) * 8;

    // prefetch tile 0
    s16x8 kr0 = ((const s16x8*)kglob)[0];
    s16x8 kr1 = ((const s16x8*)kglob)[1];
    s16x8 vr0 = *(const s16x8*)(vglob0);
    s16x8 vr1 = *(const s16x8*)(vglob0 + rs);

    int swz = l16 & 7;   // read-side swizzle key (row & 7 = l16 & 7)

    for (int kb = 0; kb < SEQ / 64; kb++) {
        int bsel = kb & 1;
        u16* ksb = &Ks[bsel][0];
        u16* vtb = &Vt[bsel][0];

        // write prefetched tile into this iteration's buffer
        *(s16x8*)(ksb + koff0) = kr0;
        *(s16x8*)(ksb + koff1) = kr1;
        u32* vt32 = (u32*)vtb;
        #pragma unroll
        for (int i = 0; i < 8; i++) {
            u32 pk = (u32)(u16)vr0[i] | ((u32)(u16)vr1[i] << 16);
            vt32[(dc + i) * (VS / 2) + vp2] = pk;
        }
        __syncthreads();   // single barrier: writes visible; prev-buf reads
                           // (iter kb-1, before its barrier) are also done

        // prefetch next tile into regs (overlaps compute)
        if (kb < SEQ / 64 - 1) {
            const u16* kp = kglob + (size_t)(kb + 1) * 64 * rs;
            const u16* vp = vglob0 + (size_t)(kb + 1) * 64 * rs;
            kr0 = ((const s16x8*)kp)[0];
            kr1 = ((const s16x8*)kp)[1];
            vr0 = *(const s16x8*)(vp);
            vr1 = *(const s16x8*)(vp + rs);
        }

        // --- S^T = K.(SCL*Q)^T - SCL ; p = exp2(s); packed P in regs ---
        s16x4 pfr[4][4];      // [rt][t]: P[qrow=l16][key=t*16+quad*4+{0..3}]
        #pragma unroll
        for (int t = 0; t < 4; t++) {
            const u16* krow = ksb + (t * 16 + l16) * 64;
            s16x8 bk0 = *(const s16x8*)(krow + ((0 + quad) ^ swz) * 8);
            s16x8 bk1 = *(const s16x8*)(krow + ((4 + quad) ^ swz) * 8);
            #pragma unroll
            for (int rt = 0; rt < 4; rt++) {
                f32x4 s = cinit;
                s = __builtin_amdgcn_mfma_f32_16x16x32_bf16(bk0, aq[rt][0], s, 0, 0, 0);
                s = __builtin_amdgcn_mfma_f32_16x16x32_bf16(bk1, aq[rt][1], s, 0, 0, 0);
                uint2 pk2;
                pk2.x = pack_bf16_pair(EXP2(s[0]), EXP2(s[1]));
                pk2.y = pack_bf16_pair(EXP2(s[2]), EXP2(s[3]));
                pfr[rt][t] = __builtin_bit_cast(s16x4, pk2);
            }
        }

        // --- O^T += V^T.P^T (+ ones sum tile), permuted key order ---
        #pragma unroll
        for (int pr = 0; pr < 2; pr++) {
            int tA = pr * 2, tB = pr * 2 + 1;
            s16x8 bp[4];
            #pragma unroll
            for (int rt = 0; rt < 4; rt++)
                bp[rt] = __builtin_shufflevector(pfr[rt][tA], pfr[rt][tB],
                                                 0, 1, 2, 3, 4, 5, 6, 7);
            #pragma unroll
            for (int ht = 0; ht < 4; ht++) {
                const u16* vrow = vtb + (ht * 16 + l16) * VS;
                s16x4 va = *(const s16x4*)(vrow + tA * 16 + quad * 4);
                s16x4 vb = *(const s16x4*)(vrow + tB * 16 + quad * 4);
                s16x8 vfr = __builtin_shufflevector(va, vb, 0, 1, 2, 3, 4, 5, 6, 7);
                #pragma unroll
                for (int rt = 0; rt < 4; rt++)
                    o2[rt][ht] = __builtin_amdgcn_mfma_f32_16x16x32_bf16(
                        vfr, bp[rt], o2[rt][ht], 0, 0, 0);
            }
            #pragma unroll
            for (int rt = 0; rt < 4; rt++)
                osum[rt] = __builtin_amdgcn_mfma_f32_16x16x32_bf16(
                    ones, bp[rt], osum[rt], 0, 0, 0);
        }
    }

    // --- epilogue: lane owns qrow=l16 (per rt), d = ht*16+quad*4+r ---
    #pragma unroll
    for (int rt = 0; rt < 4; rt++) {
        float inv = 1.0f / osum[rt][0];
        int orow = b * SEQ + qt * 256 + wave * 64 + rt * 16 + l16;
        u16* op = out + (size_t)orow * D + h * 64 + quad * 4;
        #pragma unroll
        for (int ht = 0; ht < 4; ht++) {
            f32x4 v = o2[rt][ht];
            u32 lo = pack_bf16_pair(v[0] * inv, v[1] * inv);
            u32 hi = pack_bf16_pair(v[2] * inv, v[3] * inv);
            uint2 pk = {lo, hi};
            *(uint2*)(op + ht * 16) = pk;
        }
    }
}

// ---------------------------------------------------------------------------
// launch
// ---------------------------------------------------------------------------
extern "C" void kernel_launch(void* const* d_in, const int* in_sizes, int n_in,
                              void* d_out, int out_size, void* d_ws, size_t ws_size,
                              hipStream_t stream) {
    const float* x     = (const float*)d_in[0];
    const float* ln_w  = (const float*)d_in[1];
    const float* ln_b  = (const float*)d_in[2];
    const float* qkv_w = (const float*)d_in[3];
    const float* qkv_b = (const float*)d_in[4];
    const float* out_w = (const float*)d_in[5];
    const float* out_b = (const float*)d_in[6];
    float* y = (float*)d_out;

    // workspace carve-up: qkv 48MB | h 16MB | wq 6MB | wo 2MB
    char* ws = (char*)d_ws;
    u16* qkv = (u16*)ws;
    u16* h   = (u16*)(ws + (size_t)48 * 1024 * 1024);
    u16* wq  = (u16*)(ws + (size_t)64 * 1024 * 1024);
    u16* wo  = (u16*)(ws + (size_t)70 * 1024 * 1024);
    u16* attn_out = h;

    ln_kernel<<<NTOK, 256, 0, stream>>>(x, ln_w, ln_b, h);
    cast_kernel<<<(3 * D * D) / 1024, 256, 0, stream>>>(qkv_w, wq, 3 * D * D);
    cast_kernel<<<(D * D) / 1024, 256, 0, stream>>>(out_w, wo, D * D);

    // QKV GEMM (m97 128^2) with fused k L2-normalization in the epilogue
    {
        dim3 grid(3 * D / 128, NTOK / 128);
        gemm_bf16<u16, false, true><<<grid, 256, 0, stream>>>(h, wq, qkv_b, nullptr,
                                                              qkv, NTOK, 3 * D, D);
    }

    mha_kernel<<<BATCH * NH * (SEQ / 256), 256, 0, stream>>>(qkv, attn_out);

    // out-proj GEMM (8-phase 256^2) + residual
    gemm256<float, true, false><<<(D / 256) * (NTOK / 256), 512, 0, stream>>>(
        attn_out, wo, out_b, x, y, NTOK, D, D);
}

// Round 5
// 295.629 us; speedup vs baseline: 1.0108x; 1.0108x over previous
//
#include <hip/hip_runtime.h>
#include <math.h>

// Problem constants
constexpr int D     = 1024;
constexpr int NH    = 16;
constexpr int HD    = 64;
constexpr int SEQ   = 2048;
constexpr int BATCH = 4;
constexpr int NTOK  = BATCH * SEQ;   // 8192 rows

typedef short s16x8 __attribute__((ext_vector_type(8)));
typedef short s16x4 __attribute__((ext_vector_type(4)));
typedef float f32x4 __attribute__((ext_vector_type(4)));
typedef unsigned short u16;
typedef unsigned int   u32;

#if __has_builtin(__builtin_amdgcn_exp2f)
#define EXP2(x) __builtin_amdgcn_exp2f(x)
#else
#define EXP2(x) exp2f(x)
#endif

__device__ __forceinline__ short f2bf(float f) {
    unsigned u = __float_as_uint(f);
    unsigned r = (u + 0x7FFFu + ((u >> 16) & 1u)) >> 16;   // RNE
    return (short)r;
}
__device__ __forceinline__ float bf2f(u16 s) {
    return __uint_as_float(((unsigned)s) << 16);
}

// pack hi16(f1)|hi16(f0) -> one u32 (lo = f0) via v_perm_b32
// NOTE (round-4 post-mortem): the v_cvt_pk_bf16_f32 inline-asm replacement
// produced mixed-sign garbage in P (absmax 4.9e3) -- do NOT reintroduce
// without an isolated correctness probe. This 3-instr sequence is proven.
__device__ __forceinline__ u32 pack_bf16_pair(float f0, float f1) {
    u32 a = __float_as_uint(f1) + 0x8000u;   // round half up
    u32 b = __float_as_uint(f0) + 0x8000u;
    return __builtin_amdgcn_perm(a, b, 0x07060302u);
}

__device__ __forceinline__ void async_lds16(const void* g, void* l) {
    __builtin_amdgcn_global_load_lds(
        (const __attribute__((address_space(1))) unsigned int*)g,
        (__attribute__((address_space(3))) unsigned int*)l, 16, 0, 0);
}

// ---------------------------------------------------------------------------
// Reductions (wave = 64)
// ---------------------------------------------------------------------------
__device__ __forceinline__ float block_reduce_sum(float v, float* red) {
    int lane = threadIdx.x & 63, wid = threadIdx.x >> 6;
    #pragma unroll
    for (int off = 32; off > 0; off >>= 1) v += __shfl_down(v, off, 64);
    if (lane == 0) red[wid] = v;
    __syncthreads();
    float r = red[0] + red[1] + red[2] + red[3];
    __syncthreads();
    return r;
}

// ---------------------------------------------------------------------------
// 1) LayerNorm (fp32 math) -> bf16 h
// ---------------------------------------------------------------------------
__global__ __launch_bounds__(256) void ln_kernel(const float* __restrict__ x,
                                                 const float* __restrict__ w,
                                                 const float* __restrict__ b,
                                                 u16* __restrict__ h) {
    __shared__ float red[4];
    int row = blockIdx.x;
    const float* xr = x + (size_t)row * D;
    int t = threadIdx.x;
    float v[4];
    float s = 0.f;
    #pragma unroll
    for (int i = 0; i < 4; i++) { v[i] = xr[t + 256 * i]; s += v[i]; }
    float mean = block_reduce_sum(s, red) * (1.0f / 1024.0f);
    float ss = 0.f;
    #pragma unroll
    for (int i = 0; i < 4; i++) { float d = v[i] - mean; ss += d * d; }
    float var = block_reduce_sum(ss, red) * (1.0f / 1024.0f);
    float rstd = rsqrtf(var + 1e-5f);
    u16* hr = h + (size_t)row * D;
    #pragma unroll
    for (int i = 0; i < 4; i++) {
        int c = t + 256 * i;
        hr[c] = (u16)f2bf((v[i] - mean) * rstd * w[c] + b[c]);
    }
}

// ---------------------------------------------------------------------------
// 1b) fp32 -> bf16 cast (weights); n divisible by 1024
// ---------------------------------------------------------------------------
__global__ __launch_bounds__(256) void cast_kernel(const float* __restrict__ in,
                                                   u16* __restrict__ out, int n) {
    int i = (blockIdx.x * 256 + threadIdx.x) * 4;
    if (i >= n) return;
    float4 f = *(const float4*)(in + i);
    s16x4 o4;
    o4[0] = f2bf(f.x); o4[1] = f2bf(f.y); o4[2] = f2bf(f.z); o4[3] = f2bf(f.w);
    *(s16x4*)(out + i) = o4;
}

// ---------------------------------------------------------------------------
// 2) bf16 MFMA GEMM (m97 structure, 128x128): C = A @ B^T + bias (+R).
//    Used for QKV: at K=1024 / grid 1536 (6 blocks/CU, 3 co-resident) the
//    implicit inter-block overlap beats the 256^2 8-phase template here
//    (measured 103.6 us: 1 block/CU, 1.5-round tail, A-panel L2 thrash).
//    NORMK: fused k L2-normalization (wave's 64-col span == one head).
// ---------------------------------------------------------------------------
template <typename OutT, bool RES, bool NORMK>
__global__ __launch_bounds__(256) void gemm_bf16(const u16* __restrict__ A,
                                                 const u16* __restrict__ B,
                                                 const float* __restrict__ bias,
                                                 const float* __restrict__ R,
                                                 OutT* __restrict__ C,
                                                 int M, int N, int K) {
    __shared__ u16 As[128 * 32];
    __shared__ u16 Bs[128 * 32];
    int tid = threadIdx.x, wave = tid >> 6, lane = tid & 63;
    int quad = lane >> 4, l16 = lane & 15;
    int wm = (wave & 1) * 64, wn = (wave >> 1) * 64;
    int rowBase = blockIdx.y * 128, colBase = blockIdx.x * 128;

    int srow = lane >> 2;
    int sk8  = (lane & 3) * 8;

    f32x4 acc[4][4];
    #pragma unroll
    for (int i = 0; i < 4; i++)
        #pragma unroll
        for (int j = 0; j < 4; j++)
            acc[i][j] = (f32x4){0.f, 0.f, 0.f, 0.f};

    for (int k0 = 0; k0 < K; k0 += 32) {
        __syncthreads();
        #pragma unroll
        for (int i = 0; i < 2; i++) {
            int r = wave * 32 + i * 16;
            const u16* ga = A + (size_t)(rowBase + r + srow) * K + k0 + sk8;
            async_lds16(ga, &As[r * 32]);
            const u16* gb = B + (size_t)(colBase + r + srow) * K + k0 + sk8;
            async_lds16(gb, &Bs[r * 32]);
        }
        __syncthreads();

        s16x8 af[4], bfr[4];
        #pragma unroll
        for (int t = 0; t < 4; t++) {
            af[t]  = *(const s16x8*)&As[(wm + t * 16 + l16) * 32 + quad * 8];
            bfr[t] = *(const s16x8*)&Bs[(wn + t * 16 + l16) * 32 + quad * 8];
        }
        #pragma unroll
        for (int mt = 0; mt < 4; mt++)
            #pragma unroll
            for (int nt = 0; nt < 4; nt++)
                acc[mt][nt] = __builtin_amdgcn_mfma_f32_16x16x32_bf16(
                    af[mt], bfr[nt], acc[mt][nt], 0, 0, 0);
    }

    // wave-uniform: does this wave's 64-col span hold k values?
    bool normk = NORMK && (colBase + wn) >= 1024 && (colBase + wn) < 2048;

    #pragma unroll
    for (int mt = 0; mt < 4; mt++) {
        float vals[4][4];   // [nt][r]
        #pragma unroll
        for (int nt = 0; nt < 4; nt++) {
            int gn = colBase + wn + nt * 16 + l16;
            float bv = bias[gn];
            #pragma unroll
            for (int r = 0; r < 4; r++) {
                float val = acc[mt][nt][r] + bv;
                if (RES) {
                    int gm = rowBase + wm + mt * 16 + quad * 4 + r;
                    val += R[(size_t)gm * N + gn];
                }
                vals[nt][r] = val;
            }
        }
        if (normk) {
            #pragma unroll
            for (int r = 0; r < 4; r++) {
                float ssq = 0.f;
                #pragma unroll
                for (int nt = 0; nt < 4; nt++) ssq = fmaf(vals[nt][r], vals[nt][r], ssq);
                ssq += __shfl_xor(ssq, 1, 64);
                ssq += __shfl_xor(ssq, 2, 64);
                ssq += __shfl_xor(ssq, 4, 64);
                ssq += __shfl_xor(ssq, 8, 64);
                float inv = 1.0f / fmaxf(sqrtf(ssq), 1e-12f);
                #pragma unroll
                for (int nt = 0; nt < 4; nt++) vals[nt][r] *= inv;
            }
        }
        #pragma unroll
        for (int nt = 0; nt < 4; nt++) {
            int gn = colBase + wn + nt * 16 + l16;
            int gm0 = rowBase + wm + mt * 16 + quad * 4;
            #pragma unroll
            for (int r = 0; r < 4; r++) {
                if constexpr (sizeof(OutT) == 2)
                    C[(size_t)(gm0 + r) * N + gn] = (OutT)f2bf(vals[nt][r]);
                else
                    C[(size_t)(gm0 + r) * N + gn] = vals[nt][r];
            }
        }
    }
}

// ---------------------------------------------------------------------------
// 3) 256x256 8-phase bf16 MFMA GEMM (m201 template) -- OUT-PROJ only.
// ---------------------------------------------------------------------------
__device__ __forceinline__ s16x8 rdfrag(const u16* lds, int row, int kk, int quad) {
    int byte = row * 128 + ((kk * 64 + quad * 16) ^ ((row & 7) << 4));
    return *(const s16x8*)((const char*)lds + byte);
}

__device__ __forceinline__ void stage_half_A(const u16* __restrict__ A, u16* ldsA,
                                             int rowBase, int K, int kt, int hs,
                                             int wave, int lane) {
    #pragma unroll
    for (int i = 0; i < 2; i++) {
        int c = wave * 2 + i;
        int baserow = ((c & 7) * 8) + ((c >> 3) << 7) + (hs << 6);
        int row = baserow + (lane >> 3);
        int colb = ((lane & 7) * 16) ^ ((row & 7) << 4);
        const u16* src = A + (size_t)(rowBase + row) * K + kt * 64 + (colb >> 1);
        async_lds16(src, ldsA + baserow * 64);
    }
}
__device__ __forceinline__ void stage_half_B(const u16* __restrict__ B, u16* ldsB,
                                             int colBase, int K, int kt, int hs,
                                             int wave, int lane) {
    #pragma unroll
    for (int i = 0; i < 2; i++) {
        int c = wave * 2 + i;
        int baserow = ((c & 3) * 8) + ((c >> 2) << 6) + (hs << 5);
        int row = baserow + (lane >> 3);
        int colb = ((lane & 7) * 16) ^ ((row & 7) << 4);
        const u16* src = B + (size_t)(colBase + row) * K + kt * 64 + (colb >> 1);
        async_lds16(src, ldsB + baserow * 64);
    }
}

template <typename OutT, bool RES, bool NORMK>
__global__ __launch_bounds__(512, 2) void gemm256(const u16* __restrict__ A,
                                                  const u16* __restrict__ B,
                                                  const float* __restrict__ bias,
                                                  const float* __restrict__ R,
                                                  OutT* __restrict__ C,
                                                  int M, int N, int K) {
    __shared__ u16 lds[2][2][256 * 64];   // [buf][A,B][row*64+col], 128 KiB

    int nby = M >> 8;
    int cpx = gridDim.x >> 3;
    int bid = blockIdx.x;
    int swz = (bid & 7) * cpx + (bid >> 3);
    int bx = swz / nby, by = swz % nby;   // M-fast walk: XCD reuses B panel
    int rowBase = by << 8, colBase = bx << 8;

    int tid = threadIdx.x, wave = tid >> 6, lane = tid & 63;
    int quad = lane >> 4, l16 = lane & 15;
    int wr = wave >> 2, wc = wave & 3;    // 2M x 4N wave grid
    int KT = K >> 6;                      // 64-wide K tiles

    f32x4 acc[8][4];
    #pragma unroll
    for (int m = 0; m < 8; m++)
        #pragma unroll
        for (int n = 0; n < 4; n++)
            acc[m][n] = (f32x4){0.f, 0.f, 0.f, 0.f};

    // ---- prologue: tile0 full + tile1 {A-mlo,B-nlo,A-mhi}; drain tile0 ----
    stage_half_A(A, &lds[0][0][0], rowBase, K, 0, 0, wave, lane);
    stage_half_B(B, &lds[0][1][0], colBase, K, 0, 0, wave, lane);
    stage_half_A(A, &lds[0][0][0], rowBase, K, 0, 1, wave, lane);
    stage_half_B(B, &lds[0][1][0], colBase, K, 0, 1, wave, lane);
    stage_half_A(A, &lds[1][0][0], rowBase, K, 1, 0, wave, lane);
    stage_half_B(B, &lds[1][1][0], colBase, K, 1, 0, wave, lane);
    stage_half_A(A, &lds[1][0][0], rowBase, K, 1, 1, wave, lane);
    asm volatile("s_waitcnt vmcnt(6)" ::: "memory");
    __builtin_amdgcn_s_barrier();

    for (int t = 0; t < KT; ++t) {
        int bsel = t & 1;
        u16* cA = &lds[bsel][0][0];
        u16* cB = &lds[bsel][1][0];
        u16* oB = &lds[bsel ^ 1][1][0];
        int t1 = t + 1; if (t1 >= KT) t1 -= KT;   // wrap: tail prefetch harmless
        int t2 = t + 2; if (t2 >= KT) t2 -= KT;

        s16x8 af[4][2], bf0[2][2], bf1[2][2];

        // ---- phase 1: read A m0-3 + B n0-1 (12 rd); stage B-nhi(t+1) ----
        #pragma unroll
        for (int m = 0; m < 4; m++)
            #pragma unroll
            for (int kk = 0; kk < 2; kk++)
                af[m][kk] = rdfrag(cA, wr * 128 + m * 16 + l16, kk, quad);
        #pragma unroll
        for (int n = 0; n < 2; n++)
            #pragma unroll
            for (int kk = 0; kk < 2; kk++)
                bf0[n][kk] = rdfrag(cB, wc * 64 + n * 16 + l16, kk, quad);
        stage_half_B(B, oB, colBase, K, t1, 1, wave, lane);
        __builtin_amdgcn_s_barrier();
        __builtin_amdgcn_s_setprio(1);
        #pragma unroll
        for (int kk = 0; kk < 2; kk++)
            #pragma unroll
            for (int m = 0; m < 4; m++)
                #pragma unroll
                for (int n = 0; n < 2; n++)
                    acc[m][n] = __builtin_amdgcn_mfma_f32_16x16x32_bf16(
                        af[m][kk], bf0[n][kk], acc[m][n], 0, 0, 0);
        __builtin_amdgcn_s_setprio(0);
        __builtin_amdgcn_s_barrier();

        // ---- phase 2: read B n2-3 (4 rd); stage A-mlo(t+2) ----
        #pragma unroll
        for (int n = 0; n < 2; n++)
            #pragma unroll
            for (int kk = 0; kk < 2; kk++)
                bf1[n][kk] = rdfrag(cB, wc * 64 + (n + 2) * 16 + l16, kk, quad);
        stage_half_A(A, cA, rowBase, K, t2, 0, wave, lane);
        __builtin_amdgcn_s_barrier();
        __builtin_amdgcn_s_setprio(1);
        #pragma unroll
        for (int kk = 0; kk < 2; kk++)
            #pragma unroll
            for (int m = 0; m < 4; m++)
                #pragma unroll
                for (int n = 0; n < 2; n++)
                    acc[m][n + 2] = __builtin_amdgcn_mfma_f32_16x16x32_bf16(
                        af[m][kk], bf1[n][kk], acc[m][n + 2], 0, 0, 0);
        __builtin_amdgcn_s_setprio(0);
        __builtin_amdgcn_s_barrier();

        // ---- phase 3: read A m4-7 (8 rd); stage B-nlo(t+2) ----
        #pragma unroll
        for (int m = 0; m < 4; m++)
            #pragma unroll
            for (int kk = 0; kk < 2; kk++)
                af[m][kk] = rdfrag(cA, wr * 128 + (m + 4) * 16 + l16, kk, quad);
        stage_half_B(B, cB, colBase, K, t2, 0, wave, lane);
        __builtin_amdgcn_s_barrier();
        __builtin_amdgcn_s_setprio(1);
        #pragma unroll
        for (int kk = 0; kk < 2; kk++)
            #pragma unroll
            for (int m = 0; m < 4; m++)
                #pragma unroll
                for (int n = 0; n < 2; n++)
                    acc[m + 4][n] = __builtin_amdgcn_mfma_f32_16x16x32_bf16(
                        af[m][kk], bf0[n][kk], acc[m + 4][n], 0, 0, 0);
        __builtin_amdgcn_s_setprio(0);
        __builtin_amdgcn_s_barrier();

        // ---- phase 4: no reads; stage A-mhi(t+2); vmcnt(6) checkpoint ----
        stage_half_A(A, cA, rowBase, K, t2, 1, wave, lane);
        __builtin_amdgcn_s_barrier();
        __builtin_amdgcn_s_setprio(1);
        #pragma unroll
        for (int kk = 0; kk < 2; kk++)
            #pragma unroll
            for (int m = 0; m < 4; m++)
                #pragma unroll
                for (int n = 0; n < 2; n++)
                    acc[m + 4][n + 2] = __builtin_amdgcn_mfma_f32_16x16x32_bf16(
                        af[m][kk], bf1[n][kk], acc[m + 4][n + 2], 0, 0, 0);
        __builtin_amdgcn_s_setprio(0);
        asm volatile("s_waitcnt vmcnt(6)" ::: "memory");
        __builtin_amdgcn_s_barrier();
    }
    asm volatile("s_waitcnt vmcnt(0)" ::: "memory");

    // ---- epilogue ----
    bool normk = NORMK && (colBase + wc * 64) >= 1024 && (colBase + wc * 64) < 2048;

    #pragma unroll
    for (int m = 0; m < 8; m++) {
        float vals[4][4];   // [n][r]
        #pragma unroll
        for (int n = 0; n < 4; n++) {
            int gn = colBase + wc * 64 + n * 16 + l16;
            float bv = bias[gn];
            #pragma unroll
            for (int r = 0; r < 4; r++) {
                float val = acc[m][n][r] + bv;
                if (RES) {
                    int gm = rowBase + wr * 128 + m * 16 + quad * 4 + r;
                    val += R[(size_t)gm * N + gn];
                }
                vals[n][r] = val;
            }
        }
        if (normk) {
            #pragma unroll
            for (int r = 0; r < 4; r++) {
                float ssq = 0.f;
                #pragma unroll
                for (int n = 0; n < 4; n++) ssq = fmaf(vals[n][r], vals[n][r], ssq);
                ssq += __shfl_xor(ssq, 1, 64);
                ssq += __shfl_xor(ssq, 2, 64);
                ssq += __shfl_xor(ssq, 4, 64);
                ssq += __shfl_xor(ssq, 8, 64);
                float inv = 1.0f / fmaxf(sqrtf(ssq), 1e-12f);
                #pragma unroll
                for (int n = 0; n < 4; n++) vals[n][r] *= inv;
            }
        }
        #pragma unroll
        for (int n = 0; n < 4; n++) {
            int gn = colBase + wc * 64 + n * 16 + l16;
            int gm0 = rowBase + wr * 128 + m * 16 + quad * 4;
            #pragma unroll
            for (int r = 0; r < 4; r++) {
                if constexpr (sizeof(OutT) == 2)
                    C[(size_t)(gm0 + r) * N + gn] = (OutT)f2bf(vals[n][r]);
                else
                    C[(size_t)(gm0 + r) * N + gn] = vals[n][r];
            }
        }
    }
}

// ---------------------------------------------------------------------------
// 4) MFMA flash attention v6 -- EXACT round-0 version (85.6 us proven).
//    v7 (occupancy split), v8 (single-barrier dbuf), and the cvt_pk P-pack
//    all regressed or broke; v6's schedule + pack_bf16_pair is the proven
//    local optimum.
//    Block = one (b,h) x 256 q-rows; 4 waves x 64 q-rows (4 row-tiles of 16).
//    Grid 512, XCD-swizzled: bh = blk & 63 -> all 8 q-tiles of one head land
//    on the same XCD (blk%8 invariant) -> K/V cached once per L2.
//    * Ks: [64][64] with 16B-chunk XOR swizzle -> conflict-free b128 r/w.
//    * Vt: transposed, stride 68 u16 -> 4-way write, clean b64 reads.
//    * S^T = mfma(K, SCL*Q, C=-SCL); p = exp2(s); P register-resident,
//      feeds PV via contraction-index permutation.
//    * lsum on the matrix pipe: all-ones A-frag sum tile.
//    k is pre-normalized by the QKV GEMM epilogue; q normalized here.
// ---------------------------------------------------------------------------
__global__ __launch_bounds__(256, 2) void mha_kernel(const u16* __restrict__ qkv,
                                                     u16* __restrict__ out) {
    __shared__ u16 Ks[64 * 64];       // swizzled [row][8 chunks of 8 u16]
    constexpr int VS = 68;            // Vt row stride (u16): 136 B
    __shared__ u16 Vt[64 * VS];       // V tile [d][key] (transposed)

    int bh = blockIdx.x & 63;         // XCD-locality swizzle
    int qt = blockIdx.x >> 6;         // 8 q-tiles of 256 rows
    int b  = bh >> 4, h = bh & 15;
    int tid = threadIdx.x;
    int wave = tid >> 6, lane = tid & 63;
    int quad = lane >> 4, l16 = lane & 15;

    const size_t rs = 3072;
    constexpr float SCL = 11.5415605f;   // 8 * log2(e)

    // --- Q frags: load raw q, L2-normalize in-register, fold SCL ---
    s16x8 aq[4][2];
    #pragma unroll
    for (int rt = 0; rt < 4; rt++) {
        const u16* qb = qkv + ((size_t)(b * SEQ) + qt * 256 + wave * 64 + rt * 16 + l16) * rs + h * 64;
        s16x8 r0 = *(const s16x8*)(qb + quad * 8);
        s16x8 r1 = *(const s16x8*)(qb + 32 + quad * 8);
        float f0[8], f1[8], ss = 0.f;
        #pragma unroll
        for (int i = 0; i < 8; i++) { f0[i] = bf2f((u16)r0[i]); ss = fmaf(f0[i], f0[i], ss); }
        #pragma unroll
        for (int i = 0; i < 8; i++) { f1[i] = bf2f((u16)r1[i]); ss = fmaf(f1[i], f1[i], ss); }
        ss += __shfl_xor(ss, 16, 64);
        ss += __shfl_xor(ss, 32, 64);
        float inv = SCL / fmaxf(sqrtf(ss), 1e-12f);
        #pragma unroll
        for (int i = 0; i < 8; i++) {
            aq[rt][0][i] = f2bf(f0[i] * inv);
            aq[rt][1][i] = f2bf(f1[i] * inv);
        }
    }

    const f32x4 cinit = {-SCL, -SCL, -SCL, -SCL};
    f32x4 o2[4][4];    // O^T frags: lane holds d=ht*16+quad*4+r, qrow=l16
    f32x4 osum[4];     // ones-tile accumulators: lsum[rt] = osum[rt][0]
    #pragma unroll
    for (int rt = 0; rt < 4; rt++) {
        #pragma unroll
        for (int ht = 0; ht < 4; ht++) o2[rt][ht] = (f32x4){0.f, 0.f, 0.f, 0.f};
        osum[rt] = (f32x4){0.f, 0.f, 0.f, 0.f};
    }
    s16x8 ones;
    #pragma unroll
    for (int i = 0; i < 8; i++) ones[i] = (short)0x3F80;   // bf16 1.0

    // staging assignments
    int skey = tid >> 2, c4 = tid & 3;            // K: row skey, chunks 2c4,2c4+1
    int ksw  = skey & 7;                          // K swizzle key
    int vp2 = tid >> 3, dc = (tid & 7) * 8;       // V: key pair (2vp2,2vp2+1)
    const u16* kglob  = qkv + ((size_t)(b * SEQ) + skey) * rs + 1024 + h * 64 + c4 * 16;
    const u16* vglob0 = qkv + ((size_t)(b * SEQ) + 2 * vp2) * rs + 2048 + h * 64 + dc;
    u16* kdst0 = &Ks[skey * 64 + ((2 * c4)     ^ ksw) * 8];
    u16* kdst1 = &Ks[skey * 64 + ((2 * c4 + 1) ^ ksw) * 8];
    u32* vt32 = (u32*)&Vt[0];

    // prefetch tile 0
    s16x8 kr0 = ((const s16x8*)kglob)[0];
    s16x8 kr1 = ((const s16x8*)kglob)[1];
    s16x8 vr0 = *(const s16x8*)(vglob0);
    s16x8 vr1 = *(const s16x8*)(vglob0 + rs);

    int swz = l16 & 7;   // read-side swizzle key (row & 7 = l16 & 7)

    for (int kb = 0; kb < SEQ / 64; kb++) {
        __syncthreads();   // previous tile's LDS reads done
        *(s16x8*)kdst0 = kr0;
        *(s16x8*)kdst1 = kr1;
        #pragma unroll
        for (int i = 0; i < 8; i++) {
            u32 pk = (u32)(u16)vr0[i] | ((u32)(u16)vr1[i] << 16);
            vt32[(dc + i) * (VS / 2) + vp2] = pk;
        }
        __syncthreads();

        // prefetch next tile into regs (overlaps compute)
        if (kb < SEQ / 64 - 1) {
            const u16* kp = kglob + (size_t)(kb + 1) * 64 * rs;
            const u16* vp = vglob0 + (size_t)(kb + 1) * 64 * rs;
            kr0 = ((const s16x8*)kp)[0];
            kr1 = ((const s16x8*)kp)[1];
            vr0 = *(const s16x8*)(vp);
            vr1 = *(const s16x8*)(vp + rs);
        }

        // --- S^T = K.(SCL*Q)^T - SCL ; p = exp2(s); packed P in regs ---
        s16x4 pfr[4][4];      // [rt][t]: P[qrow=l16][key=t*16+quad*4+{0..3}]
        #pragma unroll
        for (int t = 0; t < 4; t++) {
            const u16* krow = &Ks[(t * 16 + l16) * 64];
            s16x8 bk0 = *(const s16x8*)(krow + ((0 + quad) ^ swz) * 8);
            s16x8 bk1 = *(const s16x8*)(krow + ((4 + quad) ^ swz) * 8);
            #pragma unroll
            for (int rt = 0; rt < 4; rt++) {
                f32x4 s = cinit;
                s = __builtin_amdgcn_mfma_f32_16x16x32_bf16(bk0, aq[rt][0], s, 0, 0, 0);
                s = __builtin_amdgcn_mfma_f32_16x16x32_bf16(bk1, aq[rt][1], s, 0, 0, 0);
                uint2 pk2;
                pk2.x = pack_bf16_pair(EXP2(s[0]), EXP2(s[1]));
                pk2.y = pack_bf16_pair(EXP2(s[2]), EXP2(s[3]));
                pfr[rt][t] = __builtin_bit_cast(s16x4, pk2);
            }
        }

        // --- O^T += V^T.P^T (+ ones sum tile), permuted key order ---
        #pragma unroll
        for (int pr = 0; pr < 2; pr++) {
            int tA = pr * 2, tB = pr * 2 + 1;
            s16x8 bp[4];
            #pragma unroll
            for (int rt = 0; rt < 4; rt++)
                bp[rt] = __builtin_shufflevector(pfr[rt][tA], pfr[rt][tB],
                                                 0, 1, 2, 3, 4, 5, 6, 7);
            #pragma unroll
            for (int ht = 0; ht < 4; ht++) {
                const u16* vrow = &Vt[(ht * 16 + l16) * VS];
                s16x4 va = *(const s16x4*)(vrow + tA * 16 + quad * 4);
                s16x4 vb = *(const s16x4*)(vrow + tB * 16 + quad * 4);
                s16x8 vfr = __builtin_shufflevector(va, vb, 0, 1, 2, 3, 4, 5, 6, 7);
                #pragma unroll
                for (int rt = 0; rt < 4; rt++)
                    o2[rt][ht] = __builtin_amdgcn_mfma_f32_16x16x32_bf16(
                        vfr, bp[rt], o2[rt][ht], 0, 0, 0);
            }
            #pragma unroll
            for (int rt = 0; rt < 4; rt++)
                osum[rt] = __builtin_amdgcn_mfma_f32_16x16x32_bf16(
                    ones, bp[rt], osum[rt], 0, 0, 0);
        }
    }

    // --- epilogue: lane owns qrow=l16 (per rt), d = ht*16+quad*4+r ---
    #pragma unroll
    for (int rt = 0; rt < 4; rt++) {
        float inv = 1.0f / osum[rt][0];
        int orow = b * SEQ + qt * 256 + wave * 64 + rt * 16 + l16;
        u16* op = out + (size_t)orow * D + h * 64 + quad * 4;
        #pragma unroll
        for (int ht = 0; ht < 4; ht++) {
            f32x4 v = o2[rt][ht];
            u32 lo = pack_bf16_pair(v[0] * inv, v[1] * inv);
            u32 hi = pack_bf16_pair(v[2] * inv, v[3] * inv);
            uint2 pk = {lo, hi};
            *(uint2*)(op + ht * 16) = pk;
        }
    }
}

// ---------------------------------------------------------------------------
// launch
// ---------------------------------------------------------------------------
extern "C" void kernel_launch(void* const* d_in, const int* in_sizes, int n_in,
                              void* d_out, int out_size, void* d_ws, size_t ws_size,
                              hipStream_t stream) {
    const float* x     = (const float*)d_in[0];
    const float* ln_w  = (const float*)d_in[1];
    const float* ln_b  = (const float*)d_in[2];
    const float* qkv_w = (const float*)d_in[3];
    const float* qkv_b = (const float*)d_in[4];
    const float* out_w = (const float*)d_in[5];
    const float* out_b = (const float*)d_in[6];
    float* y = (float*)d_out;

    // workspace carve-up: qkv 48MB | h 16MB | wq 6MB | wo 2MB
    char* ws = (char*)d_ws;
    u16* qkv = (u16*)ws;
    u16* h   = (u16*)(ws + (size_t)48 * 1024 * 1024);
    u16* wq  = (u16*)(ws + (size_t)64 * 1024 * 1024);
    u16* wo  = (u16*)(ws + (size_t)70 * 1024 * 1024);
    u16* attn_out = h;

    ln_kernel<<<NTOK, 256, 0, stream>>>(x, ln_w, ln_b, h);
    cast_kernel<<<(3 * D * D) / 1024, 256, 0, stream>>>(qkv_w, wq, 3 * D * D);
    cast_kernel<<<(D * D) / 1024, 256, 0, stream>>>(out_w, wo, D * D);

    // QKV GEMM (m97 128^2) with fused k L2-normalization in the epilogue
    {
        dim3 grid(3 * D / 128, NTOK / 128);
        gemm_bf16<u16, false, true><<<grid, 256, 0, stream>>>(h, wq, qkv_b, nullptr,
                                                              qkv, NTOK, 3 * D, D);
    }

    mha_kernel<<<BATCH * NH * (SEQ / 256), 256, 0, stream>>>(qkv, attn_out);

    // out-proj GEMM (8-phase 256^2) + residual
    gemm256<float, true, false><<<(D / 256) * (NTOK / 256), 512, 0, stream>>>(
        attn_out, wo, out_b, x, y, NTOK, D, D);
}

// Round 6
// 289.349 us; speedup vs baseline: 1.0327x; 1.0217x over previous
//
#include <hip/hip_runtime.h>
#include <math.h>

// Problem constants
constexpr int D     = 1024;
constexpr int NH    = 16;
constexpr int HD    = 64;
constexpr int SEQ   = 2048;
constexpr int BATCH = 4;
constexpr int NTOK  = BATCH * SEQ;   // 8192 rows

typedef short s16x8 __attribute__((ext_vector_type(8)));
typedef short s16x4 __attribute__((ext_vector_type(4)));
typedef float f32x4 __attribute__((ext_vector_type(4)));
typedef unsigned short u16;
typedef unsigned int   u32;

#if __has_builtin(__builtin_amdgcn_exp2f)
#define EXP2(x) __builtin_amdgcn_exp2f(x)
#else
#define EXP2(x) exp2f(x)
#endif

__device__ __forceinline__ short f2bf(float f) {
    unsigned u = __float_as_uint(f);
    unsigned r = (u + 0x7FFFu + ((u >> 16) & 1u)) >> 16;   // RNE
    return (short)r;
}
__device__ __forceinline__ float bf2f(u16 s) {
    return __uint_as_float(((unsigned)s) << 16);
}

// pack hi16(f1)|hi16(f0) -> one u32 (lo = f0) via v_perm_b32
// NOTE (round-4 post-mortem): v_cvt_pk_bf16_f32 inline-asm replacement broke
// (likely writes lo16 only, hi16 = uninitialized garbage -> mixed-sign huge P,
// absmax 4.9e3). Do NOT reintroduce without isolated probe. This is proven.
__device__ __forceinline__ u32 pack_bf16_pair(float f0, float f1) {
    u32 a = __float_as_uint(f1) + 0x8000u;   // round half up
    u32 b = __float_as_uint(f0) + 0x8000u;
    return __builtin_amdgcn_perm(a, b, 0x07060302u);
}

__device__ __forceinline__ void async_lds16(const void* g, void* l) {
    __builtin_amdgcn_global_load_lds(
        (const __attribute__((address_space(1))) unsigned int*)g,
        (__attribute__((address_space(3))) unsigned int*)l, 16, 0, 0);
}

// ---------------------------------------------------------------------------
// Reductions (wave = 64)
// ---------------------------------------------------------------------------
__device__ __forceinline__ float block_reduce_sum(float v, float* red) {
    int lane = threadIdx.x & 63, wid = threadIdx.x >> 6;
    #pragma unroll
    for (int off = 32; off > 0; off >>= 1) v += __shfl_down(v, off, 64);
    if (lane == 0) red[wid] = v;
    __syncthreads();
    float r = red[0] + red[1] + red[2] + red[3];
    __syncthreads();
    return r;
}

// ---------------------------------------------------------------------------
// 1) Fused prep: LayerNorm (blocks [0,NTOK)) + wq cast (next 3072 blocks)
//    + wo cast (last 1024 blocks). Pure re-indexing of the three proven
//    kernels; block-uniform branch. 3 launches -> 1.
// ---------------------------------------------------------------------------
__global__ __launch_bounds__(256) void prep_kernel(const float* __restrict__ x,
                                                   const float* __restrict__ w,
                                                   const float* __restrict__ b,
                                                   u16* __restrict__ h,
                                                   const float* __restrict__ wq_in,
                                                   u16* __restrict__ wq_out,
                                                   const float* __restrict__ wo_in,
                                                   u16* __restrict__ wo_out) {
    __shared__ float red[4];
    int blk = blockIdx.x;
    int t = threadIdx.x;
    if (blk < NTOK) {
        // ---- LayerNorm row ----
        const float* xr = x + (size_t)blk * D;
        float v[4];
        float s = 0.f;
        #pragma unroll
        for (int i = 0; i < 4; i++) { v[i] = xr[t + 256 * i]; s += v[i]; }
        float mean = block_reduce_sum(s, red) * (1.0f / 1024.0f);
        float ss = 0.f;
        #pragma unroll
        for (int i = 0; i < 4; i++) { float d = v[i] - mean; ss += d * d; }
        float var = block_reduce_sum(ss, red) * (1.0f / 1024.0f);
        float rstd = rsqrtf(var + 1e-5f);
        u16* hr = h + (size_t)blk * D;
        #pragma unroll
        for (int i = 0; i < 4; i++) {
            int c = t + 256 * i;
            hr[c] = (u16)f2bf((v[i] - mean) * rstd * w[c] + b[c]);
        }
    } else if (blk < NTOK + 3072) {
        // ---- wq fp32 -> bf16 (3*D*D = 3072*1024 elems) ----
        int i = ((blk - NTOK) * 256 + t) * 4;
        float4 f = *(const float4*)(wq_in + i);
        s16x4 o4;
        o4[0] = f2bf(f.x); o4[1] = f2bf(f.y); o4[2] = f2bf(f.z); o4[3] = f2bf(f.w);
        *(s16x4*)(wq_out + i) = o4;
    } else {
        // ---- wo fp32 -> bf16 (D*D = 1024*1024 elems) ----
        int i = ((blk - NTOK - 3072) * 256 + t) * 4;
        float4 f = *(const float4*)(wo_in + i);
        s16x4 o4;
        o4[0] = f2bf(f.x); o4[1] = f2bf(f.y); o4[2] = f2bf(f.z); o4[3] = f2bf(f.w);
        *(s16x4*)(wo_out + i) = o4;
    }
}

// ---------------------------------------------------------------------------
// 2) bf16 MFMA GEMM (m97 structure, 128x128): C = A @ B^T + bias (+R).
//    Used for QKV. NORMK: fused k L2-normalization.
// ---------------------------------------------------------------------------
template <typename OutT, bool RES, bool NORMK>
__global__ __launch_bounds__(256) void gemm_bf16(const u16* __restrict__ A,
                                                 const u16* __restrict__ B,
                                                 const float* __restrict__ bias,
                                                 const float* __restrict__ R,
                                                 OutT* __restrict__ C,
                                                 int M, int N, int K) {
    __shared__ u16 As[128 * 32];
    __shared__ u16 Bs[128 * 32];
    int tid = threadIdx.x, wave = tid >> 6, lane = tid & 63;
    int quad = lane >> 4, l16 = lane & 15;
    int wm = (wave & 1) * 64, wn = (wave >> 1) * 64;
    int rowBase = blockIdx.y * 128, colBase = blockIdx.x * 128;

    int srow = lane >> 2;
    int sk8  = (lane & 3) * 8;

    f32x4 acc[4][4];
    #pragma unroll
    for (int i = 0; i < 4; i++)
        #pragma unroll
        for (int j = 0; j < 4; j++)
            acc[i][j] = (f32x4){0.f, 0.f, 0.f, 0.f};

    for (int k0 = 0; k0 < K; k0 += 32) {
        __syncthreads();
        #pragma unroll
        for (int i = 0; i < 2; i++) {
            int r = wave * 32 + i * 16;
            const u16* ga = A + (size_t)(rowBase + r + srow) * K + k0 + sk8;
            async_lds16(ga, &As[r * 32]);
            const u16* gb = B + (size_t)(colBase + r + srow) * K + k0 + sk8;
            async_lds16(gb, &Bs[r * 32]);
        }
        __syncthreads();

        s16x8 af[4], bfr[4];
        #pragma unroll
        for (int t = 0; t < 4; t++) {
            af[t]  = *(const s16x8*)&As[(wm + t * 16 + l16) * 32 + quad * 8];
            bfr[t] = *(const s16x8*)&Bs[(wn + t * 16 + l16) * 32 + quad * 8];
        }
        #pragma unroll
        for (int mt = 0; mt < 4; mt++)
            #pragma unroll
            for (int nt = 0; nt < 4; nt++)
                acc[mt][nt] = __builtin_amdgcn_mfma_f32_16x16x32_bf16(
                    af[mt], bfr[nt], acc[mt][nt], 0, 0, 0);
    }

    // wave-uniform: does this wave's 64-col span hold k values?
    bool normk = NORMK && (colBase + wn) >= 1024 && (colBase + wn) < 2048;

    #pragma unroll
    for (int mt = 0; mt < 4; mt++) {
        float vals[4][4];   // [nt][r]
        #pragma unroll
        for (int nt = 0; nt < 4; nt++) {
            int gn = colBase + wn + nt * 16 + l16;
            float bv = bias[gn];
            #pragma unroll
            for (int r = 0; r < 4; r++) {
                float val = acc[mt][nt][r] + bv;
                if (RES) {
                    int gm = rowBase + wm + mt * 16 + quad * 4 + r;
                    val += R[(size_t)gm * N + gn];
                }
                vals[nt][r] = val;
            }
        }
        if (normk) {
            #pragma unroll
            for (int r = 0; r < 4; r++) {
                float ssq = 0.f;
                #pragma unroll
                for (int nt = 0; nt < 4; nt++) ssq = fmaf(vals[nt][r], vals[nt][r], ssq);
                ssq += __shfl_xor(ssq, 1, 64);
                ssq += __shfl_xor(ssq, 2, 64);
                ssq += __shfl_xor(ssq, 4, 64);
                ssq += __shfl_xor(ssq, 8, 64);
                float inv = 1.0f / fmaxf(sqrtf(ssq), 1e-12f);
                #pragma unroll
                for (int nt = 0; nt < 4; nt++) vals[nt][r] *= inv;
            }
        }
        #pragma unroll
        for (int nt = 0; nt < 4; nt++) {
            int gn = colBase + wn + nt * 16 + l16;
            int gm0 = rowBase + wm + mt * 16 + quad * 4;
            #pragma unroll
            for (int r = 0; r < 4; r++) {
                if constexpr (sizeof(OutT) == 2)
                    C[(size_t)(gm0 + r) * N + gn] = (OutT)f2bf(vals[nt][r]);
                else
                    C[(size_t)(gm0 + r) * N + gn] = vals[nt][r];
            }
        }
    }
}

// ---------------------------------------------------------------------------
// 3) 256x256 8-phase bf16 MFMA GEMM (m201 template) -- OUT-PROJ only.
// ---------------------------------------------------------------------------
__device__ __forceinline__ s16x8 rdfrag(const u16* lds, int row, int kk, int quad) {
    int byte = row * 128 + ((kk * 64 + quad * 16) ^ ((row & 7) << 4));
    return *(const s16x8*)((const char*)lds + byte);
}

__device__ __forceinline__ void stage_half_A(const u16* __restrict__ A, u16* ldsA,
                                             int rowBase, int K, int kt, int hs,
                                             int wave, int lane) {
    #pragma unroll
    for (int i = 0; i < 2; i++) {
        int c = wave * 2 + i;
        int baserow = ((c & 7) * 8) + ((c >> 3) << 7) + (hs << 6);
        int row = baserow + (lane >> 3);
        int colb = ((lane & 7) * 16) ^ ((row & 7) << 4);
        const u16* src = A + (size_t)(rowBase + row) * K + kt * 64 + (colb >> 1);
        async_lds16(src, ldsA + baserow * 64);
    }
}
__device__ __forceinline__ void stage_half_B(const u16* __restrict__ B, u16* ldsB,
                                             int colBase, int K, int kt, int hs,
                                             int wave, int lane) {
    #pragma unroll
    for (int i = 0; i < 2; i++) {
        int c = wave * 2 + i;
        int baserow = ((c & 3) * 8) + ((c >> 2) << 6) + (hs << 5);
        int row = baserow + (lane >> 3);
        int colb = ((lane & 7) * 16) ^ ((row & 7) << 4);
        const u16* src = B + (size_t)(colBase + row) * K + kt * 64 + (colb >> 1);
        async_lds16(src, ldsB + baserow * 64);
    }
}

template <typename OutT, bool RES, bool NORMK>
__global__ __launch_bounds__(512, 2) void gemm256(const u16* __restrict__ A,
                                                  const u16* __restrict__ B,
                                                  const float* __restrict__ bias,
                                                  const float* __restrict__ R,
                                                  OutT* __restrict__ C,
                                                  int M, int N, int K) {
    __shared__ u16 lds[2][2][256 * 64];   // [buf][A,B][row*64+col], 128 KiB

    int nby = M >> 8;
    int cpx = gridDim.x >> 3;
    int bid = blockIdx.x;
    int swz = (bid & 7) * cpx + (bid >> 3);
    int bx = swz / nby, by = swz % nby;   // M-fast walk: XCD reuses B panel
    int rowBase = by << 8, colBase = bx << 8;

    int tid = threadIdx.x, wave = tid >> 6, lane = tid & 63;
    int quad = lane >> 4, l16 = lane & 15;
    int wr = wave >> 2, wc = wave & 3;    // 2M x 4N wave grid
    int KT = K >> 6;                      // 64-wide K tiles

    f32x4 acc[8][4];
    #pragma unroll
    for (int m = 0; m < 8; m++)
        #pragma unroll
        for (int n = 0; n < 4; n++)
            acc[m][n] = (f32x4){0.f, 0.f, 0.f, 0.f};

    // ---- prologue: tile0 full + tile1 {A-mlo,B-nlo,A-mhi}; drain tile0 ----
    stage_half_A(A, &lds[0][0][0], rowBase, K, 0, 0, wave, lane);
    stage_half_B(B, &lds[0][1][0], colBase, K, 0, 0, wave, lane);
    stage_half_A(A, &lds[0][0][0], rowBase, K, 0, 1, wave, lane);
    stage_half_B(B, &lds[0][1][0], colBase, K, 0, 1, wave, lane);
    stage_half_A(A, &lds[1][0][0], rowBase, K, 1, 0, wave, lane);
    stage_half_B(B, &lds[1][1][0], colBase, K, 1, 0, wave, lane);
    stage_half_A(A, &lds[1][0][0], rowBase, K, 1, 1, wave, lane);
    asm volatile("s_waitcnt vmcnt(6)" ::: "memory");
    __builtin_amdgcn_s_barrier();

    for (int t = 0; t < KT; ++t) {
        int bsel = t & 1;
        u16* cA = &lds[bsel][0][0];
        u16* cB = &lds[bsel][1][0];
        u16* oB = &lds[bsel ^ 1][1][0];
        int t1 = t + 1; if (t1 >= KT) t1 -= KT;   // wrap: tail prefetch harmless
        int t2 = t + 2; if (t2 >= KT) t2 -= KT;

        s16x8 af[4][2], bf0[2][2], bf1[2][2];

        // ---- phase 1: read A m0-3 + B n0-1 (12 rd); stage B-nhi(t+1) ----
        #pragma unroll
        for (int m = 0; m < 4; m++)
            #pragma unroll
            for (int kk = 0; kk < 2; kk++)
                af[m][kk] = rdfrag(cA, wr * 128 + m * 16 + l16, kk, quad);
        #pragma unroll
        for (int n = 0; n < 2; n++)
            #pragma unroll
            for (int kk = 0; kk < 2; kk++)
                bf0[n][kk] = rdfrag(cB, wc * 64 + n * 16 + l16, kk, quad);
        stage_half_B(B, oB, colBase, K, t1, 1, wave, lane);
        __builtin_amdgcn_s_barrier();
        __builtin_amdgcn_s_setprio(1);
        #pragma unroll
        for (int kk = 0; kk < 2; kk++)
            #pragma unroll
            for (int m = 0; m < 4; m++)
                #pragma unroll
                for (int n = 0; n < 2; n++)
                    acc[m][n] = __builtin_amdgcn_mfma_f32_16x16x32_bf16(
                        af[m][kk], bf0[n][kk], acc[m][n], 0, 0, 0);
        __builtin_amdgcn_s_setprio(0);
        __builtin_amdgcn_s_barrier();

        // ---- phase 2: read B n2-3 (4 rd); stage A-mlo(t+2) ----
        #pragma unroll
        for (int n = 0; n < 2; n++)
            #pragma unroll
            for (int kk = 0; kk < 2; kk++)
                bf1[n][kk] = rdfrag(cB, wc * 64 + (n + 2) * 16 + l16, kk, quad);
        stage_half_A(A, cA, rowBase, K, t2, 0, wave, lane);
        __builtin_amdgcn_s_barrier();
        __builtin_amdgcn_s_setprio(1);
        #pragma unroll
        for (int kk = 0; kk < 2; kk++)
            #pragma unroll
            for (int m = 0; m < 4; m++)
                #pragma unroll
                for (int n = 0; n < 2; n++)
                    acc[m][n + 2] = __builtin_amdgcn_mfma_f32_16x16x32_bf16(
                        af[m][kk], bf1[n][kk], acc[m][n + 2], 0, 0, 0);
        __builtin_amdgcn_s_setprio(0);
        __builtin_amdgcn_s_barrier();

        // ---- phase 3: read A m4-7 (8 rd); stage B-nlo(t+2) ----
        #pragma unroll
        for (int m = 0; m < 4; m++)
            #pragma unroll
            for (int kk = 0; kk < 2; kk++)
                af[m][kk] = rdfrag(cA, wr * 128 + (m + 4) * 16 + l16, kk, quad);
        stage_half_B(B, cB, colBase, K, t2, 0, wave, lane);
        __builtin_amdgcn_s_barrier();
        __builtin_amdgcn_s_setprio(1);
        #pragma unroll
        for (int kk = 0; kk < 2; kk++)
            #pragma unroll
            for (int m = 0; m < 4; m++)
                #pragma unroll
                for (int n = 0; n < 2; n++)
                    acc[m + 4][n] = __builtin_amdgcn_mfma_f32_16x16x32_bf16(
                        af[m][kk], bf0[n][kk], acc[m + 4][n], 0, 0, 0);
        __builtin_amdgcn_s_setprio(0);
        __builtin_amdgcn_s_barrier();

        // ---- phase 4: no reads; stage A-mhi(t+2); vmcnt(6) checkpoint ----
        stage_half_A(A, cA, rowBase, K, t2, 1, wave, lane);
        __builtin_amdgcn_s_barrier();
        __builtin_amdgcn_s_setprio(1);
        #pragma unroll
        for (int kk = 0; kk < 2; kk++)
            #pragma unroll
            for (int m = 0; m < 4; m++)
                #pragma unroll
                for (int n = 0; n < 2; n++)
                    acc[m + 4][n + 2] = __builtin_amdgcn_mfma_f32_16x16x32_bf16(
                        af[m][kk], bf1[n][kk], acc[m + 4][n + 2], 0, 0, 0);
        __builtin_amdgcn_s_setprio(0);
        asm volatile("s_waitcnt vmcnt(6)" ::: "memory");
        __builtin_amdgcn_s_barrier();
    }
    asm volatile("s_waitcnt vmcnt(0)" ::: "memory");

    // ---- epilogue ----
    bool normk = NORMK && (colBase + wc * 64) >= 1024 && (colBase + wc * 64) < 2048;

    #pragma unroll
    for (int m = 0; m < 8; m++) {
        float vals[4][4];   // [n][r]
        #pragma unroll
        for (int n = 0; n < 4; n++) {
            int gn = colBase + wc * 64 + n * 16 + l16;
            float bv = bias[gn];
            #pragma unroll
            for (int r = 0; r < 4; r++) {
                float val = acc[m][n][r] + bv;
                if (RES) {
                    int gm = rowBase + wr * 128 + m * 16 + quad * 4 + r;
                    val += R[(size_t)gm * N + gn];
                }
                vals[n][r] = val;
            }
        }
        if (normk) {
            #pragma unroll
            for (int r = 0; r < 4; r++) {
                float ssq = 0.f;
                #pragma unroll
                for (int n = 0; n < 4; n++) ssq = fmaf(vals[n][r], vals[n][r], ssq);
                ssq += __shfl_xor(ssq, 1, 64);
                ssq += __shfl_xor(ssq, 2, 64);
                ssq += __shfl_xor(ssq, 4, 64);
                ssq += __shfl_xor(ssq, 8, 64);
                float inv = 1.0f / fmaxf(sqrtf(ssq), 1e-12f);
                #pragma unroll
                for (int n = 0; n < 4; n++) vals[n][r] *= inv;
            }
        }
        #pragma unroll
        for (int n = 0; n < 4; n++) {
            int gn = colBase + wc * 64 + n * 16 + l16;
            int gm0 = rowBase + wr * 128 + m * 16 + quad * 4;
            #pragma unroll
            for (int r = 0; r < 4; r++) {
                if constexpr (sizeof(OutT) == 2)
                    C[(size_t)(gm0 + r) * N + gn] = (OutT)f2bf(vals[n][r]);
                else
                    C[(size_t)(gm0 + r) * N + gn] = vals[n][r];
            }
        }
    }
}

// ---------------------------------------------------------------------------
// 4) MFMA flash attention v9: v6 tile/schedule, 8 waves per block.
//    Block = one (b,h) x 256 q-rows; 8 waves x 32 q-rows (2 row-tiles of 16).
//    Grid 512 (unchanged), 512 threads -> 2 blocks/CU = 4 waves/SIMD
//    (v6 was 2 waves/SIMD, MfmaUtil 33% = dependent-MFMA-chain latency
//    exposed). K/V staging done by waves 0-3 at the IDENTICAL v6 addresses
//    -> HBM fetch + LDS-write work per block unchanged (v7's regression
//    mechanism avoided; discriminator: FETCH_SIZE stays ~24.7MB).
//    LDS reads double but LDS pipe is <10% busy. Waves 4-7 enter MFMA
//    right after the barrier while 0-3 issue prefetch (free role-split).
//    * Ks: [64][64] 16B-chunk XOR swizzle -> conflict-free b128 r/w.
//    * Vt: transposed, stride 68 u16.
//    * S^T = mfma(K, SCL*Q, C=-SCL); p = exp2(s); P register-resident.
//    * lsum via all-ones A-frag MFMA sum tile.
//    k pre-normalized by QKV GEMM epilogue; q normalized here.
// ---------------------------------------------------------------------------
__global__ __launch_bounds__(512, 4) void mha_kernel(const u16* __restrict__ qkv,
                                                     u16* __restrict__ out) {
    __shared__ u16 Ks[64 * 64];       // swizzled [row][8 chunks of 8 u16]
    constexpr int VS = 68;            // Vt row stride (u16): 136 B
    __shared__ u16 Vt[64 * VS];       // V tile [d][key] (transposed)

    int bh = blockIdx.x & 63;         // XCD-locality swizzle
    int qt = blockIdx.x >> 6;         // 8 q-tiles of 256 rows
    int b  = bh >> 4, h = bh & 15;
    int tid = threadIdx.x;
    int wave = tid >> 6, lane = tid & 63;
    int quad = lane >> 4, l16 = lane & 15;

    const size_t rs = 3072;
    constexpr float SCL = 11.5415605f;   // 8 * log2(e)

    // --- Q frags: 2 row-tiles of 16 per wave; normalize + fold SCL ---
    s16x8 aq[2][2];
    #pragma unroll
    for (int rt = 0; rt < 2; rt++) {
        const u16* qb = qkv + ((size_t)(b * SEQ) + qt * 256 + wave * 32 + rt * 16 + l16) * rs + h * 64;
        s16x8 r0 = *(const s16x8*)(qb + quad * 8);
        s16x8 r1 = *(const s16x8*)(qb + 32 + quad * 8);
        float f0[8], f1[8], ss = 0.f;
        #pragma unroll
        for (int i = 0; i < 8; i++) { f0[i] = bf2f((u16)r0[i]); ss = fmaf(f0[i], f0[i], ss); }
        #pragma unroll
        for (int i = 0; i < 8; i++) { f1[i] = bf2f((u16)r1[i]); ss = fmaf(f1[i], f1[i], ss); }
        ss += __shfl_xor(ss, 16, 64);
        ss += __shfl_xor(ss, 32, 64);
        float inv = SCL / fmaxf(sqrtf(ss), 1e-12f);
        #pragma unroll
        for (int i = 0; i < 8; i++) {
            aq[rt][0][i] = f2bf(f0[i] * inv);
            aq[rt][1][i] = f2bf(f1[i] * inv);
        }
    }

    const f32x4 cinit = {-SCL, -SCL, -SCL, -SCL};
    f32x4 o2[2][4];    // O^T frags: lane holds d=ht*16+quad*4+r, qrow=l16
    f32x4 osum[2];     // ones-tile accumulators: lsum[rt] = osum[rt][0]
    #pragma unroll
    for (int rt = 0; rt < 2; rt++) {
        #pragma unroll
        for (int ht = 0; ht < 4; ht++) o2[rt][ht] = (f32x4){0.f, 0.f, 0.f, 0.f};
        osum[rt] = (f32x4){0.f, 0.f, 0.f, 0.f};
    }
    s16x8 ones;
    #pragma unroll
    for (int i = 0; i < 8; i++) ones[i] = (short)0x3F80;   // bf16 1.0

    // staging assignments: waves 0-3 only, identical addresses to v6
    bool stager = (tid < 256);
    int st = tid & 255;
    int skey = st >> 2, c4 = st & 3;              // K: row skey, chunks 2c4,2c4+1
    int ksw  = skey & 7;                          // K swizzle key
    int vp2 = st >> 3, dc = (st & 7) * 8;         // V: key pair (2vp2,2vp2+1)
    const u16* kglob  = qkv + ((size_t)(b * SEQ) + skey) * rs + 1024 + h * 64 + c4 * 16;
    const u16* vglob0 = qkv + ((size_t)(b * SEQ) + 2 * vp2) * rs + 2048 + h * 64 + dc;
    u16* kdst0 = &Ks[skey * 64 + ((2 * c4)     ^ ksw) * 8];
    u16* kdst1 = &Ks[skey * 64 + ((2 * c4 + 1) ^ ksw) * 8];
    u32* vt32 = (u32*)&Vt[0];

    // prefetch tile 0 (stagers only)
    s16x8 kr0{}, kr1{}, vr0{}, vr1{};
    if (stager) {
        kr0 = ((const s16x8*)kglob)[0];
        kr1 = ((const s16x8*)kglob)[1];
        vr0 = *(const s16x8*)(vglob0);
        vr1 = *(const s16x8*)(vglob0 + rs);
    }

    int swz = l16 & 7;   // read-side swizzle key (row & 7 = l16 & 7)

    for (int kb = 0; kb < SEQ / 64; kb++) {
        __syncthreads();   // previous tile's LDS reads done
        if (stager) {
            *(s16x8*)kdst0 = kr0;
            *(s16x8*)kdst1 = kr1;
            #pragma unroll
            for (int i = 0; i < 8; i++) {
                u32 pk = (u32)(u16)vr0[i] | ((u32)(u16)vr1[i] << 16);
                vt32[(dc + i) * (VS / 2) + vp2] = pk;
            }
        }
        __syncthreads();

        // prefetch next tile into regs (stagers; overlaps compute of all waves)
        if (stager && kb < SEQ / 64 - 1) {
            const u16* kp = kglob + (size_t)(kb + 1) * 64 * rs;
            const u16* vp = vglob0 + (size_t)(kb + 1) * 64 * rs;
            kr0 = ((const s16x8*)kp)[0];
            kr1 = ((const s16x8*)kp)[1];
            vr0 = *(const s16x8*)(vp);
            vr1 = *(const s16x8*)(vp + rs);
        }

        // --- S^T = K.(SCL*Q)^T - SCL ; p = exp2(s); packed P in regs ---
        s16x4 pfr[2][4];      // [rt][t]: P[qrow=l16][key=t*16+quad*4+{0..3}]
        #pragma unroll
        for (int t = 0; t < 4; t++) {
            const u16* krow = &Ks[(t * 16 + l16) * 64];
            s16x8 bk0 = *(const s16x8*)(krow + ((0 + quad) ^ swz) * 8);
            s16x8 bk1 = *(const s16x8*)(krow + ((4 + quad) ^ swz) * 8);
            #pragma unroll
            for (int rt = 0; rt < 2; rt++) {
                f32x4 s = cinit;
                s = __builtin_amdgcn_mfma_f32_16x16x32_bf16(bk0, aq[rt][0], s, 0, 0, 0);
                s = __builtin_amdgcn_mfma_f32_16x16x32_bf16(bk1, aq[rt][1], s, 0, 0, 0);
                uint2 pk2;
                pk2.x = pack_bf16_pair(EXP2(s[0]), EXP2(s[1]));
                pk2.y = pack_bf16_pair(EXP2(s[2]), EXP2(s[3]));
                pfr[rt][t] = __builtin_bit_cast(s16x4, pk2);
            }
        }

        // --- O^T += V^T.P^T (+ ones sum tile), permuted key order ---
        #pragma unroll
        for (int pr = 0; pr < 2; pr++) {
            int tA = pr * 2, tB = pr * 2 + 1;
            s16x8 bp[2];
            #pragma unroll
            for (int rt = 0; rt < 2; rt++)
                bp[rt] = __builtin_shufflevector(pfr[rt][tA], pfr[rt][tB],
                                                 0, 1, 2, 3, 4, 5, 6, 7);
            #pragma unroll
            for (int ht = 0; ht < 4; ht++) {
                const u16* vrow = &Vt[(ht * 16 + l16) * VS];
                s16x4 va = *(const s16x4*)(vrow + tA * 16 + quad * 4);
                s16x4 vb = *(const s16x4*)(vrow + tB * 16 + quad * 4);
                s16x8 vfr = __builtin_shufflevector(va, vb, 0, 1, 2, 3, 4, 5, 6, 7);
                #pragma unroll
                for (int rt = 0; rt < 2; rt++)
                    o2[rt][ht] = __builtin_amdgcn_mfma_f32_16x16x32_bf16(
                        vfr, bp[rt], o2[rt][ht], 0, 0, 0);
            }
            #pragma unroll
            for (int rt = 0; rt < 2; rt++)
                osum[rt] = __builtin_amdgcn_mfma_f32_16x16x32_bf16(
                    ones, bp[rt], osum[rt], 0, 0, 0);
        }
    }

    // --- epilogue: lane owns qrow=l16 (per rt), d = ht*16+quad*4+r ---
    #pragma unroll
    for (int rt = 0; rt < 2; rt++) {
        float inv = 1.0f / osum[rt][0];
        int orow = b * SEQ + qt * 256 + wave * 32 + rt * 16 + l16;
        u16* op = out + (size_t)orow * D + h * 64 + quad * 4;
        #pragma unroll
        for (int ht = 0; ht < 4; ht++) {
            f32x4 v = o2[rt][ht];
            u32 lo = pack_bf16_pair(v[0] * inv, v[1] * inv);
            u32 hi = pack_bf16_pair(v[2] * inv, v[3] * inv);
            uint2 pk = {lo, hi};
            *(uint2*)(op + ht * 16) = pk;
        }
    }
}

// ---------------------------------------------------------------------------
// launch
// ---------------------------------------------------------------------------
extern "C" void kernel_launch(void* const* d_in, const int* in_sizes, int n_in,
                              void* d_out, int out_size, void* d_ws, size_t ws_size,
                              hipStream_t stream) {
    const float* x     = (const float*)d_in[0];
    const float* ln_w  = (const float*)d_in[1];
    const float* ln_b  = (const float*)d_in[2];
    const float* qkv_w = (const float*)d_in[3];
    const float* qkv_b = (const float*)d_in[4];
    const float* out_w = (const float*)d_in[5];
    const float* out_b = (const float*)d_in[6];
    float* y = (float*)d_out;

    // workspace carve-up: qkv 48MB | h 16MB | wq 6MB | wo 2MB
    char* ws = (char*)d_ws;
    u16* qkv = (u16*)ws;
    u16* h   = (u16*)(ws + (size_t)48 * 1024 * 1024);
    u16* wq  = (u16*)(ws + (size_t)64 * 1024 * 1024);
    u16* wo  = (u16*)(ws + (size_t)70 * 1024 * 1024);
    u16* attn_out = h;

    // fused LN + weight casts (1 launch instead of 3)
    prep_kernel<<<NTOK + 3072 + 1024, 256, 0, stream>>>(x, ln_w, ln_b, h,
                                                        qkv_w, wq, out_w, wo);

    // QKV GEMM (m97 128^2) with fused k L2-normalization in the epilogue
    {
        dim3 grid(3 * D / 128, NTOK / 128);
        gemm_bf16<u16, false, true><<<grid, 256, 0, stream>>>(h, wq, qkv_b, nullptr,
                                                              qkv, NTOK, 3 * D, D);
    }

    // flash attention v9: 8 waves/block, grid unchanged
    mha_kernel<<<BATCH * NH * (SEQ / 256), 512, 0, stream>>>(qkv, attn_out);

    // out-proj GEMM (8-phase 256^2) + residual
    gemm256<float, true, false><<<(D / 256) * (NTOK / 256), 512, 0, stream>>>(
        attn_out, wo, out_b, x, y, NTOK, D, D);
}

// Round 7
// 280.831 us; speedup vs baseline: 1.0640x; 1.0303x over previous
//
#include <hip/hip_runtime.h>
#include <math.h>

// Problem constants
constexpr int D     = 1024;
constexpr int NH    = 16;
constexpr int HD    = 64;
constexpr int SEQ   = 2048;
constexpr int BATCH = 4;
constexpr int NTOK  = BATCH * SEQ;   // 8192 rows

typedef short s16x8 __attribute__((ext_vector_type(8)));
typedef short s16x4 __attribute__((ext_vector_type(4)));
typedef float f32x4 __attribute__((ext_vector_type(4)));
typedef unsigned short u16;
typedef unsigned int   u32;

#if __has_builtin(__builtin_amdgcn_exp2f)
#define EXP2(x) __builtin_amdgcn_exp2f(x)
#else
#define EXP2(x) exp2f(x)
#endif

__device__ __forceinline__ short f2bf(float f) {
    unsigned u = __float_as_uint(f);
    unsigned r = (u + 0x7FFFu + ((u >> 16) & 1u)) >> 16;   // RNE
    return (short)r;
}
__device__ __forceinline__ float bf2f(u16 s) {
    return __uint_as_float(((unsigned)s) << 16);
}

// pack hi16(f1)|hi16(f0) -> one u32 (lo = f0) via v_perm_b32
// NOTE (round-4 post-mortem): v_cvt_pk_bf16_f32 inline-asm replacement broke
// (mixed-sign garbage in P, absmax 4.9e3). Do NOT reintroduce without an
// isolated probe. This 3-instr sequence is proven.
__device__ __forceinline__ u32 pack_bf16_pair(float f0, float f1) {
    u32 a = __float_as_uint(f1) + 0x8000u;   // round half up
    u32 b = __float_as_uint(f0) + 0x8000u;
    return __builtin_amdgcn_perm(a, b, 0x07060302u);
}

__device__ __forceinline__ void async_lds16(const void* g, void* l) {
    __builtin_amdgcn_global_load_lds(
        (const __attribute__((address_space(1))) unsigned int*)g,
        (__attribute__((address_space(3))) unsigned int*)l, 16, 0, 0);
}

// ---------------------------------------------------------------------------
// Reductions (wave = 64)
// ---------------------------------------------------------------------------
__device__ __forceinline__ float block_reduce_sum(float v, float* red) {
    int lane = threadIdx.x & 63, wid = threadIdx.x >> 6;
    #pragma unroll
    for (int off = 32; off > 0; off >>= 1) v += __shfl_down(v, off, 64);
    if (lane == 0) red[wid] = v;
    __syncthreads();
    float r = red[0] + red[1] + red[2] + red[3];
    __syncthreads();
    return r;
}

// ---------------------------------------------------------------------------
// 1) Fused prep: LayerNorm (blocks [0,NTOK)) + wq cast (next 3072 blocks)
//    + wo cast (last 1024 blocks). 3 launches -> 1. (Proven round 6.)
// ---------------------------------------------------------------------------
__global__ __launch_bounds__(256) void prep_kernel(const float* __restrict__ x,
                                                   const float* __restrict__ w,
                                                   const float* __restrict__ b,
                                                   u16* __restrict__ h,
                                                   const float* __restrict__ wq_in,
                                                   u16* __restrict__ wq_out,
                                                   const float* __restrict__ wo_in,
                                                   u16* __restrict__ wo_out) {
    __shared__ float red[4];
    int blk = blockIdx.x;
    int t = threadIdx.x;
    if (blk < NTOK) {
        // ---- LayerNorm row ----
        const float* xr = x + (size_t)blk * D;
        float v[4];
        float s = 0.f;
        #pragma unroll
        for (int i = 0; i < 4; i++) { v[i] = xr[t + 256 * i]; s += v[i]; }
        float mean = block_reduce_sum(s, red) * (1.0f / 1024.0f);
        float ss = 0.f;
        #pragma unroll
        for (int i = 0; i < 4; i++) { float d = v[i] - mean; ss += d * d; }
        float var = block_reduce_sum(ss, red) * (1.0f / 1024.0f);
        float rstd = rsqrtf(var + 1e-5f);
        u16* hr = h + (size_t)blk * D;
        #pragma unroll
        for (int i = 0; i < 4; i++) {
            int c = t + 256 * i;
            hr[c] = (u16)f2bf((v[i] - mean) * rstd * w[c] + b[c]);
        }
    } else if (blk < NTOK + 3072) {
        // ---- wq fp32 -> bf16 ----
        int i = ((blk - NTOK) * 256 + t) * 4;
        float4 f = *(const float4*)(wq_in + i);
        s16x4 o4;
        o4[0] = f2bf(f.x); o4[1] = f2bf(f.y); o4[2] = f2bf(f.z); o4[3] = f2bf(f.w);
        *(s16x4*)(wq_out + i) = o4;
    } else {
        // ---- wo fp32 -> bf16 ----
        int i = ((blk - NTOK - 3072) * 256 + t) * 4;
        float4 f = *(const float4*)(wo_in + i);
        s16x4 o4;
        o4[0] = f2bf(f.x); o4[1] = f2bf(f.y); o4[2] = f2bf(f.z); o4[3] = f2bf(f.w);
        *(s16x4*)(wo_out + i) = o4;
    }
}

// ---------------------------------------------------------------------------
// 2) bf16 MFMA GEMM (m97 structure, 128x128): C = A @ B^T + bias (+R).
//    Used for BOTH GEMMs (round-6 post-mortem: the 256^2 8-phase out-proj
//    ran 128 blocks = 1 block/CU = HALF THE CHIP IDLE, est. 60-70 us for
//    1.72e10 FLOP; m97 at 512 blocks is full-chip, est. 28-35 us).
//    NORMK: fused k L2-normalization (wave's 64-col span == one head).
// ---------------------------------------------------------------------------
template <typename OutT, bool RES, bool NORMK>
__global__ __launch_bounds__(256) void gemm_bf16(const u16* __restrict__ A,
                                                 const u16* __restrict__ B,
                                                 const float* __restrict__ bias,
                                                 const float* __restrict__ R,
                                                 OutT* __restrict__ C,
                                                 int M, int N, int K) {
    __shared__ u16 As[128 * 32];
    __shared__ u16 Bs[128 * 32];
    int tid = threadIdx.x, wave = tid >> 6, lane = tid & 63;
    int quad = lane >> 4, l16 = lane & 15;
    int wm = (wave & 1) * 64, wn = (wave >> 1) * 64;
    int rowBase = blockIdx.y * 128, colBase = blockIdx.x * 128;

    int srow = lane >> 2;
    int sk8  = (lane & 3) * 8;

    f32x4 acc[4][4];
    #pragma unroll
    for (int i = 0; i < 4; i++)
        #pragma unroll
        for (int j = 0; j < 4; j++)
            acc[i][j] = (f32x4){0.f, 0.f, 0.f, 0.f};

    for (int k0 = 0; k0 < K; k0 += 32) {
        __syncthreads();
        #pragma unroll
        for (int i = 0; i < 2; i++) {
            int r = wave * 32 + i * 16;
            const u16* ga = A + (size_t)(rowBase + r + srow) * K + k0 + sk8;
            async_lds16(ga, &As[r * 32]);
            const u16* gb = B + (size_t)(colBase + r + srow) * K + k0 + sk8;
            async_lds16(gb, &Bs[r * 32]);
        }
        __syncthreads();

        s16x8 af[4], bfr[4];
        #pragma unroll
        for (int t = 0; t < 4; t++) {
            af[t]  = *(const s16x8*)&As[(wm + t * 16 + l16) * 32 + quad * 8];
            bfr[t] = *(const s16x8*)&Bs[(wn + t * 16 + l16) * 32 + quad * 8];
        }
        #pragma unroll
        for (int mt = 0; mt < 4; mt++)
            #pragma unroll
            for (int nt = 0; nt < 4; nt++)
                acc[mt][nt] = __builtin_amdgcn_mfma_f32_16x16x32_bf16(
                    af[mt], bfr[nt], acc[mt][nt], 0, 0, 0);
    }

    // wave-uniform: does this wave's 64-col span hold k values?
    bool normk = NORMK && (colBase + wn) >= 1024 && (colBase + wn) < 2048;

    #pragma unroll
    for (int mt = 0; mt < 4; mt++) {
        float vals[4][4];   // [nt][r]
        #pragma unroll
        for (int nt = 0; nt < 4; nt++) {
            int gn = colBase + wn + nt * 16 + l16;
            float bv = bias[gn];
            #pragma unroll
            for (int r = 0; r < 4; r++) {
                float val = acc[mt][nt][r] + bv;
                if (RES) {
                    int gm = rowBase + wm + mt * 16 + quad * 4 + r;
                    val += R[(size_t)gm * N + gn];
                }
                vals[nt][r] = val;
            }
        }
        if (normk) {
            #pragma unroll
            for (int r = 0; r < 4; r++) {
                float ssq = 0.f;
                #pragma unroll
                for (int nt = 0; nt < 4; nt++) ssq = fmaf(vals[nt][r], vals[nt][r], ssq);
                ssq += __shfl_xor(ssq, 1, 64);
                ssq += __shfl_xor(ssq, 2, 64);
                ssq += __shfl_xor(ssq, 4, 64);
                ssq += __shfl_xor(ssq, 8, 64);
                float inv = 1.0f / fmaxf(sqrtf(ssq), 1e-12f);
                #pragma unroll
                for (int nt = 0; nt < 4; nt++) vals[nt][r] *= inv;
            }
        }
        #pragma unroll
        for (int nt = 0; nt < 4; nt++) {
            int gn = colBase + wn + nt * 16 + l16;
            int gm0 = rowBase + wm + mt * 16 + quad * 4;
            #pragma unroll
            for (int r = 0; r < 4; r++) {
                if constexpr (sizeof(OutT) == 2)
                    C[(size_t)(gm0 + r) * N + gn] = (OutT)f2bf(vals[nt][r]);
                else
                    C[(size_t)(gm0 + r) * N + gn] = vals[nt][r];
            }
        }
    }
}

// ---------------------------------------------------------------------------
// 3) MFMA flash attention v9 (proven round 6: 84.6 us, occ 32.6%).
//    Block = one (b,h) x 256 q-rows; 8 waves x 32 q-rows (2 row-tiles of 16).
//    Grid 512, 512 threads -> 2 blocks/CU = 4 waves/SIMD. K/V staging by
//    waves 0-3 at the v6 addresses (HBM fetch + LDS-write work unchanged).
//    * Ks: [64][64] 16B-chunk XOR swizzle -> conflict-free b128 r/w.
//    * Vt: transposed, stride 68 u16.
//    * S^T = mfma(K, SCL*Q, C=-SCL); p = exp2(s); P register-resident.
//    * lsum via all-ones A-frag MFMA sum tile.
//    k pre-normalized by QKV GEMM epilogue; q normalized here.
// ---------------------------------------------------------------------------
__global__ __launch_bounds__(512, 4) void mha_kernel(const u16* __restrict__ qkv,
                                                     u16* __restrict__ out) {
    __shared__ u16 Ks[64 * 64];       // swizzled [row][8 chunks of 8 u16]
    constexpr int VS = 68;            // Vt row stride (u16): 136 B
    __shared__ u16 Vt[64 * VS];       // V tile [d][key] (transposed)

    int bh = blockIdx.x & 63;         // XCD-locality swizzle
    int qt = blockIdx.x >> 6;         // 8 q-tiles of 256 rows
    int b  = bh >> 4, h = bh & 15;
    int tid = threadIdx.x;
    int wave = tid >> 6, lane = tid & 63;
    int quad = lane >> 4, l16 = lane & 15;

    const size_t rs = 3072;
    constexpr float SCL = 11.5415605f;   // 8 * log2(e)

    // --- Q frags: 2 row-tiles of 16 per wave; normalize + fold SCL ---
    s16x8 aq[2][2];
    #pragma unroll
    for (int rt = 0; rt < 2; rt++) {
        const u16* qb = qkv + ((size_t)(b * SEQ) + qt * 256 + wave * 32 + rt * 16 + l16) * rs + h * 64;
        s16x8 r0 = *(const s16x8*)(qb + quad * 8);
        s16x8 r1 = *(const s16x8*)(qb + 32 + quad * 8);
        float f0[8], f1[8], ss = 0.f;
        #pragma unroll
        for (int i = 0; i < 8; i++) { f0[i] = bf2f((u16)r0[i]); ss = fmaf(f0[i], f0[i], ss); }
        #pragma unroll
        for (int i = 0; i < 8; i++) { f1[i] = bf2f((u16)r1[i]); ss = fmaf(f1[i], f1[i], ss); }
        ss += __shfl_xor(ss, 16, 64);
        ss += __shfl_xor(ss, 32, 64);
        float inv = SCL / fmaxf(sqrtf(ss), 1e-12f);
        #pragma unroll
        for (int i = 0; i < 8; i++) {
            aq[rt][0][i] = f2bf(f0[i] * inv);
            aq[rt][1][i] = f2bf(f1[i] * inv);
        }
    }

    const f32x4 cinit = {-SCL, -SCL, -SCL, -SCL};
    f32x4 o2[2][4];    // O^T frags: lane holds d=ht*16+quad*4+r, qrow=l16
    f32x4 osum[2];     // ones-tile accumulators: lsum[rt] = osum[rt][0]
    #pragma unroll
    for (int rt = 0; rt < 2; rt++) {
        #pragma unroll
        for (int ht = 0; ht < 4; ht++) o2[rt][ht] = (f32x4){0.f, 0.f, 0.f, 0.f};
        osum[rt] = (f32x4){0.f, 0.f, 0.f, 0.f};
    }
    s16x8 ones;
    #pragma unroll
    for (int i = 0; i < 8; i++) ones[i] = (short)0x3F80;   // bf16 1.0

    // staging assignments: waves 0-3 only, identical addresses to v6
    bool stager = (tid < 256);
    int st = tid & 255;
    int skey = st >> 2, c4 = st & 3;              // K: row skey, chunks 2c4,2c4+1
    int ksw  = skey & 7;                          // K swizzle key
    int vp2 = st >> 3, dc = (st & 7) * 8;         // V: key pair (2vp2,2vp2+1)
    const u16* kglob  = qkv + ((size_t)(b * SEQ) + skey) * rs + 1024 + h * 64 + c4 * 16;
    const u16* vglob0 = qkv + ((size_t)(b * SEQ) + 2 * vp2) * rs + 2048 + h * 64 + dc;
    u16* kdst0 = &Ks[skey * 64 + ((2 * c4)     ^ ksw) * 8];
    u16* kdst1 = &Ks[skey * 64 + ((2 * c4 + 1) ^ ksw) * 8];
    u32* vt32 = (u32*)&Vt[0];

    // prefetch tile 0 (stagers only)
    s16x8 kr0{}, kr1{}, vr0{}, vr1{};
    if (stager) {
        kr0 = ((const s16x8*)kglob)[0];
        kr1 = ((const s16x8*)kglob)[1];
        vr0 = *(const s16x8*)(vglob0);
        vr1 = *(const s16x8*)(vglob0 + rs);
    }

    int swz = l16 & 7;   // read-side swizzle key (row & 7 = l16 & 7)

    for (int kb = 0; kb < SEQ / 64; kb++) {
        __syncthreads();   // previous tile's LDS reads done
        if (stager) {
            *(s16x8*)kdst0 = kr0;
            *(s16x8*)kdst1 = kr1;
            #pragma unroll
            for (int i = 0; i < 8; i++) {
                u32 pk = (u32)(u16)vr0[i] | ((u32)(u16)vr1[i] << 16);
                vt32[(dc + i) * (VS / 2) + vp2] = pk;
            }
        }
        __syncthreads();

        // prefetch next tile into regs (stagers; overlaps compute of all waves)
        if (stager && kb < SEQ / 64 - 1) {
            const u16* kp = kglob + (size_t)(kb + 1) * 64 * rs;
            const u16* vp = vglob0 + (size_t)(kb + 1) * 64 * rs;
            kr0 = ((const s16x8*)kp)[0];
            kr1 = ((const s16x8*)kp)[1];
            vr0 = *(const s16x8*)(vp);
            vr1 = *(const s16x8*)(vp + rs);
        }

        // --- S^T = K.(SCL*Q)^T - SCL ; p = exp2(s); packed P in regs ---
        s16x4 pfr[2][4];      // [rt][t]: P[qrow=l16][key=t*16+quad*4+{0..3}]
        #pragma unroll
        for (int t = 0; t < 4; t++) {
            const u16* krow = &Ks[(t * 16 + l16) * 64];
            s16x8 bk0 = *(const s16x8*)(krow + ((0 + quad) ^ swz) * 8);
            s16x8 bk1 = *(const s16x8*)(krow + ((4 + quad) ^ swz) * 8);
            #pragma unroll
            for (int rt = 0; rt < 2; rt++) {
                f32x4 s = cinit;
                s = __builtin_amdgcn_mfma_f32_16x16x32_bf16(bk0, aq[rt][0], s, 0, 0, 0);
                s = __builtin_amdgcn_mfma_f32_16x16x32_bf16(bk1, aq[rt][1], s, 0, 0, 0);
                uint2 pk2;
                pk2.x = pack_bf16_pair(EXP2(s[0]), EXP2(s[1]));
                pk2.y = pack_bf16_pair(EXP2(s[2]), EXP2(s[3]));
                pfr[rt][t] = __builtin_bit_cast(s16x4, pk2);
            }
        }

        // --- O^T += V^T.P^T (+ ones sum tile), permuted key order ---
        #pragma unroll
        for (int pr = 0; pr < 2; pr++) {
            int tA = pr * 2, tB = pr * 2 + 1;
            s16x8 bp[2];
            #pragma unroll
            for (int rt = 0; rt < 2; rt++)
                bp[rt] = __builtin_shufflevector(pfr[rt][tA], pfr[rt][tB],
                                                 0, 1, 2, 3, 4, 5, 6, 7);
            #pragma unroll
            for (int ht = 0; ht < 4; ht++) {
                const u16* vrow = &Vt[(ht * 16 + l16) * VS];
                s16x4 va = *(const s16x4*)(vrow + tA * 16 + quad * 4);
                s16x4 vb = *(const s16x4*)(vrow + tB * 16 + quad * 4);
                s16x8 vfr = __builtin_shufflevector(va, vb, 0, 1, 2, 3, 4, 5, 6, 7);
                #pragma unroll
                for (int rt = 0; rt < 2; rt++)
                    o2[rt][ht] = __builtin_amdgcn_mfma_f32_16x16x32_bf16(
                        vfr, bp[rt], o2[rt][ht], 0, 0, 0);
            }
            #pragma unroll
            for (int rt = 0; rt < 2; rt++)
                osum[rt] = __builtin_amdgcn_mfma_f32_16x16x32_bf16(
                    ones, bp[rt], osum[rt], 0, 0, 0);
        }
    }

    // --- epilogue: lane owns qrow=l16 (per rt), d = ht*16+quad*4+r ---
    #pragma unroll
    for (int rt = 0; rt < 2; rt++) {
        float inv = 1.0f / osum[rt][0];
        int orow = b * SEQ + qt * 256 + wave * 32 + rt * 16 + l16;
        u16* op = out + (size_t)orow * D + h * 64 + quad * 4;
        #pragma unroll
        for (int ht = 0; ht < 4; ht++) {
            f32x4 v = o2[rt][ht];
            u32 lo = pack_bf16_pair(v[0] * inv, v[1] * inv);
            u32 hi = pack_bf16_pair(v[2] * inv, v[3] * inv);
            uint2 pk = {lo, hi};
            *(uint2*)(op + ht * 16) = pk;
        }
    }
}

// ---------------------------------------------------------------------------
// launch
// ---------------------------------------------------------------------------
extern "C" void kernel_launch(void* const* d_in, const int* in_sizes, int n_in,
                              void* d_out, int out_size, void* d_ws, size_t ws_size,
                              hipStream_t stream) {
    const float* x     = (const float*)d_in[0];
    const float* ln_w  = (const float*)d_in[1];
    const float* ln_b  = (const float*)d_in[2];
    const float* qkv_w = (const float*)d_in[3];
    const float* qkv_b = (const float*)d_in[4];
    const float* out_w = (const float*)d_in[5];
    const float* out_b = (const float*)d_in[6];
    float* y = (float*)d_out;

    // workspace carve-up: qkv 48MB | h 16MB | wq 6MB | wo 2MB
    char* ws = (char*)d_ws;
    u16* qkv = (u16*)ws;
    u16* h   = (u16*)(ws + (size_t)48 * 1024 * 1024);
    u16* wq  = (u16*)(ws + (size_t)64 * 1024 * 1024);
    u16* wo  = (u16*)(ws + (size_t)70 * 1024 * 1024);
    u16* attn_out = h;

    // fused LN + weight casts (1 launch instead of 3)
    prep_kernel<<<NTOK + 3072 + 1024, 256, 0, stream>>>(x, ln_w, ln_b, h,
                                                        qkv_w, wq, out_w, wo);

    // QKV GEMM (m97 128^2) with fused k L2-normalization in the epilogue
    {
        dim3 grid(3 * D / 128, NTOK / 128);
        gemm_bf16<u16, false, true><<<grid, 256, 0, stream>>>(h, wq, qkv_b, nullptr,
                                                              qkv, NTOK, 3 * D, D);
    }

    // flash attention v9
    mha_kernel<<<BATCH * NH * (SEQ / 256), 512, 0, stream>>>(qkv, attn_out);

    // out-proj GEMM (m97 128^2, 512 blocks full-chip) + residual
    {
        dim3 grid(D / 128, NTOK / 128);
        gemm_bf16<float, true, false><<<grid, 256, 0, stream>>>(attn_out, wo, out_b,
                                                                x, y, NTOK, D, D);
    }
}

// Round 8
// 270.516 us; speedup vs baseline: 1.1046x; 1.0381x over previous
//
#include <hip/hip_runtime.h>
#include <math.h>

// Problem constants
constexpr int D     = 1024;
constexpr int NH    = 16;
constexpr int HD    = 64;
constexpr int SEQ   = 2048;
constexpr int BATCH = 4;
constexpr int NTOK  = BATCH * SEQ;   // 8192 rows

typedef short s16x8 __attribute__((ext_vector_type(8)));
typedef short s16x4 __attribute__((ext_vector_type(4)));
typedef float f32x4 __attribute__((ext_vector_type(4)));
typedef unsigned short u16;
typedef unsigned int   u32;

#if __has_builtin(__builtin_amdgcn_exp2f)
#define EXP2(x) __builtin_amdgcn_exp2f(x)
#else
#define EXP2(x) exp2f(x)
#endif

__device__ __forceinline__ short f2bf(float f) {
    unsigned u = __float_as_uint(f);
    unsigned r = (u + 0x7FFFu + ((u >> 16) & 1u)) >> 16;   // RNE
    return (short)r;
}
__device__ __forceinline__ float bf2f(u16 s) {
    return __uint_as_float(((unsigned)s) << 16);
}

// pack hi16(f1)|hi16(f0) -> one u32 (lo = f0) via v_perm_b32
// NOTE (round-4 post-mortem): v_cvt_pk_bf16_f32 inline-asm replacement broke
// (mixed-sign garbage in P, absmax 4.9e3). Do NOT reintroduce without an
// isolated probe. This 3-instr sequence is proven.
__device__ __forceinline__ u32 pack_bf16_pair(float f0, float f1) {
    u32 a = __float_as_uint(f1) + 0x8000u;   // round half up
    u32 b = __float_as_uint(f0) + 0x8000u;
    return __builtin_amdgcn_perm(a, b, 0x07060302u);
}

__device__ __forceinline__ void async_lds16(const void* g, void* l) {
    __builtin_amdgcn_global_load_lds(
        (const __attribute__((address_space(1))) unsigned int*)g,
        (__attribute__((address_space(3))) unsigned int*)l, 16, 0, 0);
}

// swizzled fragment read for 64-u16 (128B) LDS rows: 2-way bank spread (free)
__device__ __forceinline__ s16x8 rdfrag(const u16* lds, int row, int kk, int quad) {
    int byte = row * 128 + ((kk * 64 + quad * 16) ^ ((row & 7) << 4));
    return *(const s16x8*)((const char*)lds + byte);
}

// ---------------------------------------------------------------------------
// Reductions (wave = 64)
// ---------------------------------------------------------------------------
__device__ __forceinline__ float block_reduce_sum(float v, float* red) {
    int lane = threadIdx.x & 63, wid = threadIdx.x >> 6;
    #pragma unroll
    for (int off = 32; off > 0; off >>= 1) v += __shfl_down(v, off, 64);
    if (lane == 0) red[wid] = v;
    __syncthreads();
    float r = red[0] + red[1] + red[2] + red[3];
    __syncthreads();
    return r;
}

// ---------------------------------------------------------------------------
// 1) Fused prep: LayerNorm (blocks [0,NTOK)) + wq cast (next 3072 blocks)
//    + wo cast (last 1024 blocks). 3 launches -> 1. (Proven round 6.)
// ---------------------------------------------------------------------------
__global__ __launch_bounds__(256) void prep_kernel(const float* __restrict__ x,
                                                   const float* __restrict__ w,
                                                   const float* __restrict__ b,
                                                   u16* __restrict__ h,
                                                   const float* __restrict__ wq_in,
                                                   u16* __restrict__ wq_out,
                                                   const float* __restrict__ wo_in,
                                                   u16* __restrict__ wo_out) {
    __shared__ float red[4];
    int blk = blockIdx.x;
    int t = threadIdx.x;
    if (blk < NTOK) {
        // ---- LayerNorm row ----
        const float* xr = x + (size_t)blk * D;
        float v[4];
        float s = 0.f;
        #pragma unroll
        for (int i = 0; i < 4; i++) { v[i] = xr[t + 256 * i]; s += v[i]; }
        float mean = block_reduce_sum(s, red) * (1.0f / 1024.0f);
        float ss = 0.f;
        #pragma unroll
        for (int i = 0; i < 4; i++) { float d = v[i] - mean; ss += d * d; }
        float var = block_reduce_sum(ss, red) * (1.0f / 1024.0f);
        float rstd = rsqrtf(var + 1e-5f);
        u16* hr = h + (size_t)blk * D;
        #pragma unroll
        for (int i = 0; i < 4; i++) {
            int c = t + 256 * i;
            hr[c] = (u16)f2bf((v[i] - mean) * rstd * w[c] + b[c]);
        }
    } else if (blk < NTOK + 3072) {
        // ---- wq fp32 -> bf16 ----
        int i = ((blk - NTOK) * 256 + t) * 4;
        float4 f = *(const float4*)(wq_in + i);
        s16x4 o4;
        o4[0] = f2bf(f.x); o4[1] = f2bf(f.y); o4[2] = f2bf(f.z); o4[3] = f2bf(f.w);
        *(s16x4*)(wq_out + i) = o4;
    } else {
        // ---- wo fp32 -> bf16 ----
        int i = ((blk - NTOK - 3072) * 256 + t) * 4;
        float4 f = *(const float4*)(wo_in + i);
        s16x4 o4;
        o4[0] = f2bf(f.x); o4[1] = f2bf(f.y); o4[2] = f2bf(f.z); o4[3] = f2bf(f.w);
        *(s16x4*)(wo_out + i) = o4;
    }
}

// ---------------------------------------------------------------------------
// 2a) bf16 MFMA GEMM, m97 structure BK=64 (QKV): C = A @ B^T + bias.
//    vs BK=32: halves the per-K-loop barrier-drain count (16 vs 32 pairs),
//    2x MFMA per drain (32/iter). LDS 32 KB (2-3 blocks/CU, same effective
//    occupancy as BK=32's measured 2.3). 128-B LDS rows would be 16-way
//    bank-conflicted; fixed by the (row&7)<<4 XOR swizzle with
//    inverse-swizzled global_load_lds source -- the stage/rdfrag pair
//    reused VERBATIM from the correctness-proven gemm256 (rounds 2-7).
//    NORMK: fused k L2-normalization (wave's 64-col span == one head).
// ---------------------------------------------------------------------------
template <typename OutT, bool RES, bool NORMK>
__global__ __launch_bounds__(256) void gemm_bk64(const u16* __restrict__ A,
                                                 const u16* __restrict__ B,
                                                 const float* __restrict__ bias,
                                                 const float* __restrict__ R,
                                                 OutT* __restrict__ C,
                                                 int M, int N, int K) {
    __shared__ u16 As[128 * 64];   // 16 KB, swizzled 128B rows
    __shared__ u16 Bs[128 * 64];
    int tid = threadIdx.x, wave = tid >> 6, lane = tid & 63;
    int quad = lane >> 4, l16 = lane & 15;
    int wm = (wave & 1) * 64, wn = (wave >> 1) * 64;
    int rowBase = blockIdx.y * 128, colBase = blockIdx.x * 128;

    f32x4 acc[4][4];
    #pragma unroll
    for (int i = 0; i < 4; i++)
        #pragma unroll
        for (int j = 0; j < 4; j++)
            acc[i][j] = (f32x4){0.f, 0.f, 0.f, 0.f};

    for (int k0 = 0; k0 < K; k0 += 64) {
        __syncthreads();
        #pragma unroll
        for (int i = 0; i < 4; i++) {
            int c = wave * 4 + i;
            int baserow = c * 8;
            int row = baserow + (lane >> 3);
            int colb = ((lane & 7) * 16) ^ ((row & 7) << 4);
            const u16* ga = A + (size_t)(rowBase + row) * K + k0 + (colb >> 1);
            async_lds16(ga, &As[baserow * 64]);
            const u16* gb = B + (size_t)(colBase + row) * K + k0 + (colb >> 1);
            async_lds16(gb, &Bs[baserow * 64]);
        }
        __syncthreads();

        s16x8 af[4][2], bfr[4][2];
        #pragma unroll
        for (int t = 0; t < 4; t++)
            #pragma unroll
            for (int kk = 0; kk < 2; kk++) {
                af[t][kk]  = rdfrag(As, wm + t * 16 + l16, kk, quad);
                bfr[t][kk] = rdfrag(Bs, wn + t * 16 + l16, kk, quad);
            }
        #pragma unroll
        for (int kk = 0; kk < 2; kk++)
            #pragma unroll
            for (int mt = 0; mt < 4; mt++)
                #pragma unroll
                for (int nt = 0; nt < 4; nt++)
                    acc[mt][nt] = __builtin_amdgcn_mfma_f32_16x16x32_bf16(
                        af[mt][kk], bfr[nt][kk], acc[mt][nt], 0, 0, 0);
    }

    // wave-uniform: does this wave's 64-col span hold k values?
    bool normk = NORMK && (colBase + wn) >= 1024 && (colBase + wn) < 2048;

    #pragma unroll
    for (int mt = 0; mt < 4; mt++) {
        float vals[4][4];   // [nt][r]
        #pragma unroll
        for (int nt = 0; nt < 4; nt++) {
            int gn = colBase + wn + nt * 16 + l16;
            float bv = bias[gn];
            #pragma unroll
            for (int r = 0; r < 4; r++) {
                float val = acc[mt][nt][r] + bv;
                if (RES) {
                    int gm = rowBase + wm + mt * 16 + quad * 4 + r;
                    val += R[(size_t)gm * N + gn];
                }
                vals[nt][r] = val;
            }
        }
        if (normk) {
            #pragma unroll
            for (int r = 0; r < 4; r++) {
                float ssq = 0.f;
                #pragma unroll
                for (int nt = 0; nt < 4; nt++) ssq = fmaf(vals[nt][r], vals[nt][r], ssq);
                ssq += __shfl_xor(ssq, 1, 64);
                ssq += __shfl_xor(ssq, 2, 64);
                ssq += __shfl_xor(ssq, 4, 64);
                ssq += __shfl_xor(ssq, 8, 64);
                float inv = 1.0f / fmaxf(sqrtf(ssq), 1e-12f);
                #pragma unroll
                for (int nt = 0; nt < 4; nt++) vals[nt][r] *= inv;
            }
        }
        #pragma unroll
        for (int nt = 0; nt < 4; nt++) {
            int gn = colBase + wn + nt * 16 + l16;
            int gm0 = rowBase + wm + mt * 16 + quad * 4;
            #pragma unroll
            for (int r = 0; r < 4; r++) {
                if constexpr (sizeof(OutT) == 2)
                    C[(size_t)(gm0 + r) * N + gn] = (OutT)f2bf(vals[nt][r]);
                else
                    C[(size_t)(gm0 + r) * N + gn] = vals[nt][r];
            }
        }
    }
}

// ---------------------------------------------------------------------------
// 2b) bf16 MFMA GEMM (m97 structure, BK=32, 128x128) -- OUT-PROJ (proven).
// ---------------------------------------------------------------------------
template <typename OutT, bool RES, bool NORMK>
__global__ __launch_bounds__(256) void gemm_bf16(const u16* __restrict__ A,
                                                 const u16* __restrict__ B,
                                                 const float* __restrict__ bias,
                                                 const float* __restrict__ R,
                                                 OutT* __restrict__ C,
                                                 int M, int N, int K) {
    __shared__ u16 As[128 * 32];
    __shared__ u16 Bs[128 * 32];
    int tid = threadIdx.x, wave = tid >> 6, lane = tid & 63;
    int quad = lane >> 4, l16 = lane & 15;
    int wm = (wave & 1) * 64, wn = (wave >> 1) * 64;
    int rowBase = blockIdx.y * 128, colBase = blockIdx.x * 128;

    int srow = lane >> 2;
    int sk8  = (lane & 3) * 8;

    f32x4 acc[4][4];
    #pragma unroll
    for (int i = 0; i < 4; i++)
        #pragma unroll
        for (int j = 0; j < 4; j++)
            acc[i][j] = (f32x4){0.f, 0.f, 0.f, 0.f};

    for (int k0 = 0; k0 < K; k0 += 32) {
        __syncthreads();
        #pragma unroll
        for (int i = 0; i < 2; i++) {
            int r = wave * 32 + i * 16;
            const u16* ga = A + (size_t)(rowBase + r + srow) * K + k0 + sk8;
            async_lds16(ga, &As[r * 32]);
            const u16* gb = B + (size_t)(colBase + r + srow) * K + k0 + sk8;
            async_lds16(gb, &Bs[r * 32]);
        }
        __syncthreads();

        s16x8 af[4], bfr[4];
        #pragma unroll
        for (int t = 0; t < 4; t++) {
            af[t]  = *(const s16x8*)&As[(wm + t * 16 + l16) * 32 + quad * 8];
            bfr[t] = *(const s16x8*)&Bs[(wn + t * 16 + l16) * 32 + quad * 8];
        }
        #pragma unroll
        for (int mt = 0; mt < 4; mt++)
            #pragma unroll
            for (int nt = 0; nt < 4; nt++)
                acc[mt][nt] = __builtin_amdgcn_mfma_f32_16x16x32_bf16(
                    af[mt], bfr[nt], acc[mt][nt], 0, 0, 0);
    }

    bool normk = NORMK && (colBase + wn) >= 1024 && (colBase + wn) < 2048;

    #pragma unroll
    for (int mt = 0; mt < 4; mt++) {
        float vals[4][4];   // [nt][r]
        #pragma unroll
        for (int nt = 0; nt < 4; nt++) {
            int gn = colBase + wn + nt * 16 + l16;
            float bv = bias[gn];
            #pragma unroll
            for (int r = 0; r < 4; r++) {
                float val = acc[mt][nt][r] + bv;
                if (RES) {
                    int gm = rowBase + wm + mt * 16 + quad * 4 + r;
                    val += R[(size_t)gm * N + gn];
                }
                vals[nt][r] = val;
            }
        }
        if (normk) {
            #pragma unroll
            for (int r = 0; r < 4; r++) {
                float ssq = 0.f;
                #pragma unroll
                for (int nt = 0; nt < 4; nt++) ssq = fmaf(vals[nt][r], vals[nt][r], ssq);
                ssq += __shfl_xor(ssq, 1, 64);
                ssq += __shfl_xor(ssq, 2, 64);
                ssq += __shfl_xor(ssq, 4, 64);
                ssq += __shfl_xor(ssq, 8, 64);
                float inv = 1.0f / fmaxf(sqrtf(ssq), 1e-12f);
                #pragma unroll
                for (int nt = 0; nt < 4; nt++) vals[nt][r] *= inv;
            }
        }
        #pragma unroll
        for (int nt = 0; nt < 4; nt++) {
            int gn = colBase + wn + nt * 16 + l16;
            int gm0 = rowBase + wm + mt * 16 + quad * 4;
            #pragma unroll
            for (int r = 0; r < 4; r++) {
                if constexpr (sizeof(OutT) == 2)
                    C[(size_t)(gm0 + r) * N + gn] = (OutT)f2bf(vals[nt][r]);
                else
                    C[(size_t)(gm0 + r) * N + gn] = vals[nt][r];
            }
        }
    }
}

// ---------------------------------------------------------------------------
// 3) MFMA flash attention v9 (proven rounds 6-7: ~84.3 us, occ ~33%).
//    Block = one (b,h) x 256 q-rows; 8 waves x 32 q-rows (2 row-tiles of 16).
//    Grid 512, 512 threads -> 2 blocks/CU = 4 waves/SIMD. K/V staging by
//    waves 0-3 at the v6 addresses (HBM fetch + LDS-write work unchanged).
// ---------------------------------------------------------------------------
__global__ __launch_bounds__(512, 4) void mha_kernel(const u16* __restrict__ qkv,
                                                     u16* __restrict__ out) {
    __shared__ u16 Ks[64 * 64];       // swizzled [row][8 chunks of 8 u16]
    constexpr int VS = 68;            // Vt row stride (u16): 136 B
    __shared__ u16 Vt[64 * VS];       // V tile [d][key] (transposed)

    int bh = blockIdx.x & 63;         // XCD-locality swizzle
    int qt = blockIdx.x >> 6;         // 8 q-tiles of 256 rows
    int b  = bh >> 4, h = bh & 15;
    int tid = threadIdx.x;
    int wave = tid >> 6, lane = tid & 63;
    int quad = lane >> 4, l16 = lane & 15;

    const size_t rs = 3072;
    constexpr float SCL = 11.5415605f;   // 8 * log2(e)

    // --- Q frags: 2 row-tiles of 16 per wave; normalize + fold SCL ---
    s16x8 aq[2][2];
    #pragma unroll
    for (int rt = 0; rt < 2; rt++) {
        const u16* qb = qkv + ((size_t)(b * SEQ) + qt * 256 + wave * 32 + rt * 16 + l16) * rs + h * 64;
        s16x8 r0 = *(const s16x8*)(qb + quad * 8);
        s16x8 r1 = *(const s16x8*)(qb + 32 + quad * 8);
        float f0[8], f1[8], ss = 0.f;
        #pragma unroll
        for (int i = 0; i < 8; i++) { f0[i] = bf2f((u16)r0[i]); ss = fmaf(f0[i], f0[i], ss); }
        #pragma unroll
        for (int i = 0; i < 8; i++) { f1[i] = bf2f((u16)r1[i]); ss = fmaf(f1[i], f1[i], ss); }
        ss += __shfl_xor(ss, 16, 64);
        ss += __shfl_xor(ss, 32, 64);
        float inv = SCL / fmaxf(sqrtf(ss), 1e-12f);
        #pragma unroll
        for (int i = 0; i < 8; i++) {
            aq[rt][0][i] = f2bf(f0[i] * inv);
            aq[rt][1][i] = f2bf(f1[i] * inv);
        }
    }

    const f32x4 cinit = {-SCL, -SCL, -SCL, -SCL};
    f32x4 o2[2][4];    // O^T frags: lane holds d=ht*16+quad*4+r, qrow=l16
    f32x4 osum[2];     // ones-tile accumulators: lsum[rt] = osum[rt][0]
    #pragma unroll
    for (int rt = 0; rt < 2; rt++) {
        #pragma unroll
        for (int ht = 0; ht < 4; ht++) o2[rt][ht] = (f32x4){0.f, 0.f, 0.f, 0.f};
        osum[rt] = (f32x4){0.f, 0.f, 0.f, 0.f};
    }
    s16x8 ones;
    #pragma unroll
    for (int i = 0; i < 8; i++) ones[i] = (short)0x3F80;   // bf16 1.0

    // staging assignments: waves 0-3 only, identical addresses to v6
    bool stager = (tid < 256);
    int st = tid & 255;
    int skey = st >> 2, c4 = st & 3;              // K: row skey, chunks 2c4,2c4+1
    int ksw  = skey & 7;                          // K swizzle key
    int vp2 = st >> 3, dc = (st & 7) * 8;         // V: key pair (2vp2,2vp2+1)
    const u16* kglob  = qkv + ((size_t)(b * SEQ) + skey) * rs + 1024 + h * 64 + c4 * 16;
    const u16* vglob0 = qkv + ((size_t)(b * SEQ) + 2 * vp2) * rs + 2048 + h * 64 + dc;
    u16* kdst0 = &Ks[skey * 64 + ((2 * c4)     ^ ksw) * 8];
    u16* kdst1 = &Ks[skey * 64 + ((2 * c4 + 1) ^ ksw) * 8];
    u32* vt32 = (u32*)&Vt[0];

    // prefetch tile 0 (stagers only)
    s16x8 kr0{}, kr1{}, vr0{}, vr1{};
    if (stager) {
        kr0 = ((const s16x8*)kglob)[0];
        kr1 = ((const s16x8*)kglob)[1];
        vr0 = *(const s16x8*)(vglob0);
        vr1 = *(const s16x8*)(vglob0 + rs);
    }

    int swz = l16 & 7;   // read-side swizzle key (row & 7 = l16 & 7)

    for (int kb = 0; kb < SEQ / 64; kb++) {
        __syncthreads();   // previous tile's LDS reads done
        if (stager) {
            *(s16x8*)kdst0 = kr0;
            *(s16x8*)kdst1 = kr1;
            #pragma unroll
            for (int i = 0; i < 8; i++) {
                u32 pk = (u32)(u16)vr0[i] | ((u32)(u16)vr1[i] << 16);
                vt32[(dc + i) * (VS / 2) + vp2] = pk;
            }
        }
        __syncthreads();

        // prefetch next tile into regs (stagers; overlaps compute of all waves)
        if (stager && kb < SEQ / 64 - 1) {
            const u16* kp = kglob + (size_t)(kb + 1) * 64 * rs;
            const u16* vp = vglob0 + (size_t)(kb + 1) * 64 * rs;
            kr0 = ((const s16x8*)kp)[0];
            kr1 = ((const s16x8*)kp)[1];
            vr0 = *(const s16x8*)(vp);
            vr1 = *(const s16x8*)(vp + rs);
        }

        // --- S^T = K.(SCL*Q)^T - SCL ; p = exp2(s); packed P in regs ---
        s16x4 pfr[2][4];      // [rt][t]: P[qrow=l16][key=t*16+quad*4+{0..3}]
        #pragma unroll
        for (int t = 0; t < 4; t++) {
            const u16* krow = &Ks[(t * 16 + l16) * 64];
            s16x8 bk0 = *(const s16x8*)(krow + ((0 + quad) ^ swz) * 8);
            s16x8 bk1 = *(const s16x8*)(krow + ((4 + quad) ^ swz) * 8);
            #pragma unroll
            for (int rt = 0; rt < 2; rt++) {
                f32x4 s = cinit;
                s = __builtin_amdgcn_mfma_f32_16x16x32_bf16(bk0, aq[rt][0], s, 0, 0, 0);
                s = __builtin_amdgcn_mfma_f32_16x16x32_bf16(bk1, aq[rt][1], s, 0, 0, 0);
                uint2 pk2;
                pk2.x = pack_bf16_pair(EXP2(s[0]), EXP2(s[1]));
                pk2.y = pack_bf16_pair(EXP2(s[2]), EXP2(s[3]));
                pfr[rt][t] = __builtin_bit_cast(s16x4, pk2);
            }
        }

        // --- O^T += V^T.P^T (+ ones sum tile), permuted key order ---
        #pragma unroll
        for (int pr = 0; pr < 2; pr++) {
            int tA = pr * 2, tB = pr * 2 + 1;
            s16x8 bp[2];
            #pragma unroll
            for (int rt = 0; rt < 2; rt++)
                bp[rt] = __builtin_shufflevector(pfr[rt][tA], pfr[rt][tB],
                                                 0, 1, 2, 3, 4, 5, 6, 7);
            #pragma unroll
            for (int ht = 0; ht < 4; ht++) {
                const u16* vrow = &Vt[(ht * 16 + l16) * VS];
                s16x4 va = *(const s16x4*)(vrow + tA * 16 + quad * 4);
                s16x4 vb = *(const s16x4*)(vrow + tB * 16 + quad * 4);
                s16x8 vfr = __builtin_shufflevector(va, vb, 0, 1, 2, 3, 4, 5, 6, 7);
                #pragma unroll
                for (int rt = 0; rt < 2; rt++)
                    o2[rt][ht] = __builtin_amdgcn_mfma_f32_16x16x32_bf16(
                        vfr, bp[rt], o2[rt][ht], 0, 0, 0);
            }
            #pragma unroll
            for (int rt = 0; rt < 2; rt++)
                osum[rt] = __builtin_amdgcn_mfma_f32_16x16x32_bf16(
                    ones, bp[rt], osum[rt], 0, 0, 0);
        }
    }

    // --- epilogue: lane owns qrow=l16 (per rt), d = ht*16+quad*4+r ---
    #pragma unroll
    for (int rt = 0; rt < 2; rt++) {
        float inv = 1.0f / osum[rt][0];
        int orow = b * SEQ + qt * 256 + wave * 32 + rt * 16 + l16;
        u16* op = out + (size_t)orow * D + h * 64 + quad * 4;
        #pragma unroll
        for (int ht = 0; ht < 4; ht++) {
            f32x4 v = o2[rt][ht];
            u32 lo = pack_bf16_pair(v[0] * inv, v[1] * inv);
            u32 hi = pack_bf16_pair(v[2] * inv, v[3] * inv);
            uint2 pk = {lo, hi};
            *(uint2*)(op + ht * 16) = pk;
        }
    }
}

// ---------------------------------------------------------------------------
// launch
// ---------------------------------------------------------------------------
extern "C" void kernel_launch(void* const* d_in, const int* in_sizes, int n_in,
                              void* d_out, int out_size, void* d_ws, size_t ws_size,
                              hipStream_t stream) {
    const float* x     = (const float*)d_in[0];
    const float* ln_w  = (const float*)d_in[1];
    const float* ln_b  = (const float*)d_in[2];
    const float* qkv_w = (const float*)d_in[3];
    const float* qkv_b = (const float*)d_in[4];
    const float* out_w = (const float*)d_in[5];
    const float* out_b = (const float*)d_in[6];
    float* y = (float*)d_out;

    // workspace carve-up: qkv 48MB | h 16MB | wq 6MB | wo 2MB
    char* ws = (char*)d_ws;
    u16* qkv = (u16*)ws;
    u16* h   = (u16*)(ws + (size_t)48 * 1024 * 1024);
    u16* wq  = (u16*)(ws + (size_t)64 * 1024 * 1024);
    u16* wo  = (u16*)(ws + (size_t)70 * 1024 * 1024);
    u16* attn_out = h;

    // fused LN + weight casts (1 launch instead of 3)
    prep_kernel<<<NTOK + 3072 + 1024, 256, 0, stream>>>(x, ln_w, ln_b, h,
                                                        qkv_w, wq, out_w, wo);

    // QKV GEMM (m97 BK=64) with fused k L2-normalization in the epilogue
    {
        dim3 grid(3 * D / 128, NTOK / 128);
        gemm_bk64<u16, false, true><<<grid, 256, 0, stream>>>(h, wq, qkv_b, nullptr,
                                                              qkv, NTOK, 3 * D, D);
    }

    // flash attention v9
    mha_kernel<<<BATCH * NH * (SEQ / 256), 512, 0, stream>>>(qkv, attn_out);

    // out-proj GEMM (m97 BK=32, 512 blocks full-chip) + residual
    {
        dim3 grid(D / 128, NTOK / 128);
        gemm_bf16<float, true, false><<<grid, 256, 0, stream>>>(attn_out, wo, out_b,
                                                                x, y, NTOK, D, D);
    }
}